// Round 2
// baseline (1778.751 us; speedup 1.0000x reference)
//
#include <hip/hip_runtime.h>

#define NPTS 4096
#define NQ   8192      // B*N
#define DD   64
#define KNN  16
#define KC   8
#define NSEG 16
#define SEGLEN 256     // NPTS/NSEG
#define FPAD 68        // 67 features + 1 pad (f2 pad slot holds n2)
#define VOFF 1048576   // B*128*N, float offset of v_world in d_out

__device__ inline float leakyf(float x) { return x > 0.f ? x : 0.1f * x; }

template<int K>
__device__ inline void topk_ins(float (&dv)[K], int (&iv)[K], float d, int m) {
  if (d < dv[K-1]) {
    float vd = d; int vi = m;
#pragma unroll
    for (int s = 0; s < K; ++s) {
      if (vd < dv[s]) {
        float td = dv[s]; int ti = iv[s];
        dv[s] = vd; iv[s] = vi; vd = td; vi = ti;
      }
    }
  }
}

// ---------------- prep: transposes + weighted features + norms ----------------
__global__ __launch_bounds__(256) void k_prep(
    const float* __restrict__ xyz1, const float* __restrict__ xyz2,
    const float* __restrict__ pts1, const float* __restrict__ pts2,
    const float* __restrict__ w_xyz_p, const float* __restrict__ w_points_p,
    float* __restrict__ f1, float* __restrict__ f2,
    float* __restrict__ n1,
    float* __restrict__ p1t, float* __restrict__ p2t,
    float* __restrict__ x1t, float* __restrict__ x2t)
{
  int gid = blockIdx.x * 256 + threadIdx.x;   // 0..8191
  int b = gid >> 12, n = gid & (NPTS - 1);
  float wx = w_xyz_p[0], wp = w_points_p[0];
  {
    const float* xb = xyz1 + (size_t)b * 3 * NPTS;
    float x = xb[n], y = xb[NPTS + n], z = xb[2 * NPTS + n];
    float nrm2 = fmaf(z, z, fmaf(y, y, x * x));
    float4 xv; xv.x = x; xv.y = y; xv.z = z; xv.w = nrm2;
    *(float4*)&x1t[(size_t)gid * 4] = xv;
    float fx = wx * x, fy = wx * y, fz = wx * z;
    float acc = fmaf(fz, fz, fmaf(fy, fy, fx * fx));
    float* fr = f1 + (size_t)gid * FPAD;
    fr[0] = fx; fr[1] = fy; fr[2] = fz;
    const float* pb = pts1 + (size_t)b * DD * NPTS;
    float* pr = p1t + (size_t)gid * DD;
    for (int c = 0; c < DD; ++c) {
      float v = pb[(size_t)c * NPTS + n];
      pr[c] = v;
      float fv = wp * v;
      fr[3 + c] = fv;
      acc = fmaf(fv, fv, acc);
    }
    fr[67] = 0.f;           // query pad must stay 0
    n1[gid] = acc;
  }
  {
    const float* xb = xyz2 + (size_t)b * 3 * NPTS;
    float x = xb[n], y = xb[NPTS + n], z = xb[2 * NPTS + n];
    float nrm2 = fmaf(z, z, fmaf(y, y, x * x));
    float4 xv; xv.x = x; xv.y = y; xv.z = z; xv.w = nrm2;
    *(float4*)&x2t[(size_t)gid * 4] = xv;
    float fx = wx * x, fy = wx * y, fz = wx * z;
    float acc = fmaf(fz, fz, fmaf(fy, fy, fx * fx));
    float* fr = f2 + (size_t)gid * FPAD;
    fr[0] = fx; fr[1] = fy; fr[2] = fz;
    const float* pb = pts2 + (size_t)b * DD * NPTS;
    float* pr = p2t + (size_t)gid * DD;
    for (int c = 0; c < DD; ++c) {
      float v = pb[(size_t)c * NPTS + n];
      pr[c] = v;
      float fv = wp * v;
      fr[3 + c] = fv;
      acc = fmaf(fv, fv, acc);
    }
    fr[67] = acc;           // candidate pad carries n2 (rides the last s_load)
  }
}

// ---------------- knn over [x,y,z,norm2] rows, partial per segment ----------------
// Candidate addresses are wave-uniform (blockIdx/loop only) -> s_load broadcast.
template<int K>
__global__ __launch_bounds__(256) void k_knn_pt(
    const float* __restrict__ x4, float* __restrict__ pd, int* __restrict__ pi)
{
  int seg = blockIdx.y;
  int Q = blockIdx.x * 256 + threadIdx.x;
  int b = Q >> 12;
  float4 q = *(const float4*)&x4[(size_t)Q * 4];
  float dv[K]; int iv[K];
#pragma unroll
  for (int s = 0; s < K; ++s) { dv[s] = 3.4e38f; iv[s] = 0; }
  int gbase = (b << 12) + seg * SEGLEN;
  int m0 = seg * SEGLEN;
  for (int j = 0; j < SEGLEN; ++j) {
    float4 c = *(const float4*)&x4[(size_t)(gbase + j) * 4];   // uniform
    float dot = fmaf(q.z, c.z, fmaf(q.y, c.y, q.x * c.x));
    float d = fmaxf(q.w + c.w - 2.f * dot, 0.f);
    topk_ins<K>(dv, iv, d, m0 + j);
  }
  float* pdq = pd + ((size_t)Q * NSEG + seg) * 16;
  int* piq = pi + ((size_t)Q * NSEG + seg) * 16;
#pragma unroll
  for (int s = 0; s < K; ++s) { pdq[s] = dv[s]; piq[s] = iv[s]; }
}

// ---------------- merge K=8 + rigid velocity regression (+ padded v4 out) ----------------
__global__ __launch_bounds__(256) void k_rigid(
    const float* __restrict__ pd, const int* __restrict__ pi,
    const float* __restrict__ x4, const float* __restrict__ vel1,
    float* __restrict__ vout, float* __restrict__ v4out)
{
  int Q = blockIdx.x * 256 + threadIdx.x;
  int b = Q >> 12;
  float dv[KC]; int iv[KC];
#pragma unroll
  for (int s = 0; s < KC; ++s) { dv[s] = 3.4e38f; iv[s] = 0; }
  for (int s = 0; s < NSEG; ++s) {
    const float* pdq = pd + ((size_t)Q * NSEG + s) * 16;
    const int* piq = pi + ((size_t)Q * NSEG + s) * 16;
#pragma unroll
    for (int j = 0; j < KC; ++j) topk_ins<KC>(dv, iv, pdq[j], piq[j]);
  }
  int base = b << 12;
  double a00 = 0, a01 = 0, a02 = 0, a11 = 0, a12 = 0, a22 = 0;
  double r0 = 0, r1 = 0, r2 = 0;
#pragma unroll
  for (int t = 0; t < KC; ++t) {
    float4 c = *(const float4*)&x4[(size_t)(base + iv[t]) * 4];
    float nr = sqrtf(c.w);
    float ux = c.x / nr, uy = c.y / nr, uz = c.z / nr;
    float cv = vel1[base + iv[t]];
    double dx = ux, dy = uy, dz = uz, dvv = cv;
    a00 += dx * dx; a01 += dx * dy; a02 += dx * dz;
    a11 += dy * dy; a12 += dy * dz; a22 += dz * dz;
    r0 += dx * dvv; r1 += dy * dvv; r2 += dz * dvv;
  }
  a00 += 1e-6; a11 += 1e-6; a22 += 1e-6;
  double c00 = a11 * a22 - a12 * a12;
  double c01 = a02 * a12 - a01 * a22;
  double c02 = a01 * a12 - a02 * a11;
  double c11 = a00 * a22 - a02 * a02;
  double c12 = a02 * a01 - a00 * a12;
  double c22 = a00 * a11 - a01 * a01;
  double det = a00 * c00 + a01 * c01 + a02 * c02;
  double inv = 1.0 / det;
  float vx = (float)((c00 * r0 + c01 * r1 + c02 * r2) * inv);
  float vy = (float)((c01 * r0 + c11 * r1 + c12 * r2) * inv);
  float vz = (float)((c02 * r0 + c12 * r1 + c22 * r2) * inv);
  vout[(size_t)Q * 3 + 0] = vx;
  vout[(size_t)Q * 3 + 1] = vy;
  vout[(size_t)Q * 3 + 2] = vz;
  float4 v; v.x = vx; v.y = vy; v.z = vz;
  v.w = fmaf(vz, vz, fmaf(vy, vy, vx * vx));
  *(float4*)&v4out[(size_t)Q * 4] = v;
}

// ---------------- knn over 67-dim features (K=16), partial per segment ----------------
// q[17] float4 (~68 VGPR) + dv/iv (32) must stay in registers: launch_bounds(256,1)
// lifts the VGPR cap. Candidate rows read at wave-uniform addresses -> s_load.
__global__ __launch_bounds__(256, 1) void k_knnf(
    const float* __restrict__ f1, const float* __restrict__ f2,
    const float* __restrict__ n1,
    float* __restrict__ pd, int* __restrict__ pi)
{
  int seg = blockIdx.y;
  int Q = blockIdx.x * 256 + threadIdx.x;
  int b = Q >> 12;
  float4 q[17];
#pragma unroll
  for (int c4 = 0; c4 < 17; ++c4)
    q[c4] = *(const float4*)&f1[(size_t)Q * FPAD + c4 * 4];
  float qn = n1[Q];
  float dv[KNN]; int iv[KNN];
#pragma unroll
  for (int s = 0; s < KNN; ++s) { dv[s] = 3.4e38f; iv[s] = 0; }
  int gbase = (b << 12) + seg * SEGLEN;
  int m0 = seg * SEGLEN;
  for (int j = 0; j < SEGLEN; ++j) {
    const float4* cf = (const float4*)&f2[(size_t)(gbase + j) * FPAD];  // uniform
    float d0 = 0.f, d1 = 0.f, d2 = 0.f, d3 = 0.f;
#pragma unroll
    for (int c4 = 0; c4 < 16; c4 += 4) {
      float4 ca = cf[c4 + 0];
      d0 = fmaf(q[c4].x, ca.x, d0); d0 = fmaf(q[c4].y, ca.y, d0);
      d0 = fmaf(q[c4].z, ca.z, d0); d0 = fmaf(q[c4].w, ca.w, d0);
      float4 cb = cf[c4 + 1];
      d1 = fmaf(q[c4+1].x, cb.x, d1); d1 = fmaf(q[c4+1].y, cb.y, d1);
      d1 = fmaf(q[c4+1].z, cb.z, d1); d1 = fmaf(q[c4+1].w, cb.w, d1);
      float4 cc = cf[c4 + 2];
      d2 = fmaf(q[c4+2].x, cc.x, d2); d2 = fmaf(q[c4+2].y, cc.y, d2);
      d2 = fmaf(q[c4+2].z, cc.z, d2); d2 = fmaf(q[c4+2].w, cc.w, d2);
      float4 cd = cf[c4 + 3];
      d3 = fmaf(q[c4+3].x, cd.x, d3); d3 = fmaf(q[c4+3].y, cd.y, d3);
      d3 = fmaf(q[c4+3].z, cd.z, d3); d3 = fmaf(q[c4+3].w, cd.w, d3);
    }
    float4 ce = cf[16];                    // {f64,f65,f66, n2}
    d0 = fmaf(q[16].x, ce.x, d0);
    d1 = fmaf(q[16].y, ce.y, d1);
    d2 = fmaf(q[16].z, ce.z, d2);
    float dot = (d0 + d1) + (d2 + d3);
    float d = fmaxf(qn + ce.w - 2.f * dot, 0.f);
    topk_ins<KNN>(dv, iv, d, m0 + j);
  }
  float* pdq = pd + ((size_t)Q * NSEG + seg) * 16;
  int* piq = pi + ((size_t)Q * NSEG + seg) * 16;
#pragma unroll
  for (int s = 0; s < KNN; ++s) { pdq[s] = dv[s]; piq[s] = iv[s]; }
}

// ---------------- merge K=16 → final indices ----------------
__global__ __launch_bounds__(256) void k_merge16(
    const float* __restrict__ pd, const int* __restrict__ pi, int* __restrict__ oidx)
{
  int Q = blockIdx.x * 256 + threadIdx.x;
  float dv[KNN]; int iv[KNN];
#pragma unroll
  for (int s = 0; s < KNN; ++s) { dv[s] = 3.4e38f; iv[s] = 0; }
  for (int s = 0; s < NSEG; ++s) {
    const float* pdq = pd + ((size_t)Q * NSEG + s) * 16;
    const int* piq = pi + ((size_t)Q * NSEG + s) * 16;
#pragma unroll
    for (int j = 0; j < KNN; ++j) topk_ins<KNN>(dv, iv, pdq[j], piq[j]);
  }
#pragma unroll
  for (int j = 0; j < KNN; ++j) oidx[(size_t)Q * KNN + j] = iv[j];
}

// ---------------- fused cost-volume MLP + weightnet1 + k-sum ----------------
__global__ __launch_bounds__(256) void k_mlp(
    const float* __restrict__ p1t, const float* __restrict__ p2t,
    const float* __restrict__ x1t, const float* __restrict__ x2t,
    const int* __restrict__ kidx,
    const float* __restrict__ W1, const float* __restrict__ B1v,
    const float* __restrict__ W2, const float* __restrict__ B2v,
    const float* __restrict__ wnw1, const float* __restrict__ wnb1,
    const float* __restrict__ wnw2, const float* __restrict__ wnb2,
    const float* __restrict__ wnw3, const float* __restrict__ wnb3,
    float* __restrict__ ptp)
{
  __shared__ __align__(16) float s_p1[64];
  __shared__ __align__(16) float s_g2t[64][20];
  __shared__ __align__(16) float s_dirt[3][20];
  __shared__ __align__(16) float s_h1t[128][20];
  __shared__ __align__(16) float s_wn[16][8];
  __shared__ __align__(16) float s_red[2][128];
  int gid = blockIdx.x, b = gid >> 12, tid = threadIdx.x;
  int ch = tid & 127, kh = tid >> 7, kb = kh * 8;

  if (tid < 16) ((float4*)s_p1)[tid] = *(const float4*)&p1t[(size_t)gid * 64 + tid * 4];
  int k_ld = tid >> 4, c_ld = (tid & 15) * 4;
  int m = kidx[(size_t)gid * 16 + k_ld];
  int grow = (b << 12) + m;
  float4 gv = *(const float4*)&p2t[(size_t)grow * 64 + c_ld];
  s_g2t[c_ld + 0][k_ld] = gv.x;
  s_g2t[c_ld + 1][k_ld] = gv.y;
  s_g2t[c_ld + 2][k_ld] = gv.z;
  s_g2t[c_ld + 3][k_ld] = gv.w;
  if ((tid & 15) == 0) {
    float4 c2 = *(const float4*)&x2t[(size_t)grow * 4];
    float4 c1 = *(const float4*)&x1t[(size_t)gid * 4];
    s_dirt[0][k_ld] = c2.x - c1.x;
    s_dirt[1][k_ld] = c2.y - c1.y;
    s_dirt[2][k_ld] = c2.z - c1.z;
  }
  __syncthreads();
  if (tid < 16) {
    float dx = s_dirt[0][tid], dy = s_dirt[1][tid], dz = s_dirt[2][tid];
    float h1w[8];
#pragma unroll
    for (int j = 0; j < 8; ++j)
      h1w[j] = fmaxf(fmaf(dz, wnw1[16 + j], fmaf(dy, wnw1[8 + j], fmaf(dx, wnw1[j], wnb1[j]))), 0.f);
#pragma unroll
    for (int j = 0; j < 8; ++j) {
      float a = wnb2[j];
#pragma unroll
      for (int qq = 0; qq < 8; ++qq) a = fmaf(h1w[qq], wnw2[qq * 8 + j], a);
      s_wn[tid][j] = fmaxf(a, 0.f);
    }
  }
  // layer1 p1-center part (same for all k)
  float pre = B1v[ch];
#pragma unroll
  for (int c4 = 0; c4 < 16; ++c4) {
    float4 p = ((float4*)s_p1)[c4];
    const float* wr = &W1[(size_t)c4 * 4 * 128 + ch];
    pre = fmaf(p.x, wr[0], pre);
    pre = fmaf(p.y, wr[128], pre);
    pre = fmaf(p.z, wr[256], pre);
    pre = fmaf(p.w, wr[384], pre);
  }
  float acc[8];
#pragma unroll
  for (int j = 0; j < 8; ++j) acc[j] = pre;
  for (int c = 0; c < 64; ++c) {
    float4 g0 = *(const float4*)&s_g2t[c][kb];
    float4 g1 = *(const float4*)&s_g2t[c][kb + 4];
    float w = W1[(size_t)(64 + c) * 128 + ch];
    acc[0] = fmaf(g0.x, w, acc[0]); acc[1] = fmaf(g0.y, w, acc[1]);
    acc[2] = fmaf(g0.z, w, acc[2]); acc[3] = fmaf(g0.w, w, acc[3]);
    acc[4] = fmaf(g1.x, w, acc[4]); acc[5] = fmaf(g1.y, w, acc[5]);
    acc[6] = fmaf(g1.z, w, acc[6]); acc[7] = fmaf(g1.w, w, acc[7]);
  }
#pragma unroll
  for (int jd = 0; jd < 3; ++jd) {
    float4 d0 = *(const float4*)&s_dirt[jd][kb];
    float4 d1 = *(const float4*)&s_dirt[jd][kb + 4];
    float w = W1[(size_t)(128 + jd) * 128 + ch];
    acc[0] = fmaf(d0.x, w, acc[0]); acc[1] = fmaf(d0.y, w, acc[1]);
    acc[2] = fmaf(d0.z, w, acc[2]); acc[3] = fmaf(d0.w, w, acc[3]);
    acc[4] = fmaf(d1.x, w, acc[4]); acc[5] = fmaf(d1.y, w, acc[5]);
    acc[6] = fmaf(d1.z, w, acc[6]); acc[7] = fmaf(d1.w, w, acc[7]);
  }
#pragma unroll
  for (int j = 0; j < 8; ++j) s_h1t[ch][kb + j] = leakyf(acc[j]);
  __syncthreads();
  float acc2[8];
  float b2 = B2v[ch];
#pragma unroll
  for (int j = 0; j < 8; ++j) acc2[j] = b2;
  for (int c = 0; c < 128; ++c) {
    float4 h0 = *(const float4*)&s_h1t[c][kb];
    float4 h1 = *(const float4*)&s_h1t[c][kb + 4];
    float w = W2[(size_t)c * 128 + ch];
    acc2[0] = fmaf(h0.x, w, acc2[0]); acc2[1] = fmaf(h0.y, w, acc2[1]);
    acc2[2] = fmaf(h0.z, w, acc2[2]); acc2[3] = fmaf(h0.w, w, acc2[3]);
    acc2[4] = fmaf(h1.x, w, acc2[4]); acc2[5] = fmaf(h1.y, w, acc2[5]);
    acc2[6] = fmaf(h1.z, w, acc2[6]); acc2[7] = fmaf(h1.w, w, acc2[7]);
  }
  float r = 0.f;
#pragma unroll
  for (int j = 0; j < 8; ++j) {
    float v = leakyf(acc2[j]);
    int k = kb + j;
    float4 wa = *(const float4*)&s_wn[k][0];
    float4 wb = *(const float4*)&s_wn[k][4];
    float wv = wnb3[ch];
    wv = fmaf(wa.x, wnw3[ch], wv);
    wv = fmaf(wa.y, wnw3[128 + ch], wv);
    wv = fmaf(wa.z, wnw3[256 + ch], wv);
    wv = fmaf(wa.w, wnw3[384 + ch], wv);
    wv = fmaf(wb.x, wnw3[512 + ch], wv);
    wv = fmaf(wb.y, wnw3[640 + ch], wv);
    wv = fmaf(wb.z, wnw3[768 + ch], wv);
    wv = fmaf(wb.w, wnw3[896 + ch], wv);
    wv = fmaxf(wv, 0.f);
    r = fmaf(wv, v, r);
  }
  s_red[kh][ch] = r;
  __syncthreads();
  if (tid < 128) ptp[(size_t)gid * 128 + tid] = s_red[0][tid] + s_red[1][tid];
}

// ---------------- final: weightnet2 + gather + k-sum + transpose store ----------------
__global__ __launch_bounds__(256) void k_final(
    const float* __restrict__ x1t, const int* __restrict__ idx2,
    const float* __restrict__ ptp,
    const float* __restrict__ wnw1, const float* __restrict__ wnb1,
    const float* __restrict__ wnw2, const float* __restrict__ wnb2,
    const float* __restrict__ wnw3, const float* __restrict__ wnb3,
    float* __restrict__ out0)
{
  __shared__ __align__(16) float s_gc[16][128];
  __shared__ __align__(16) float s_wn[16][8];
  __shared__ __align__(16) float s_red[2][128];
  int gid = blockIdx.x, b = gid >> 12, n = gid & (NPTS - 1);
  int tid = threadIdx.x;
  if (tid < 16) {
    int m = idx2[(size_t)gid * 16 + tid];
    float4 c2 = *(const float4*)&x1t[(size_t)((b << 12) + m) * 4];
    float4 c1 = *(const float4*)&x1t[(size_t)gid * 4];
    float dx = c2.x - c1.x, dy = c2.y - c1.y, dz = c2.z - c1.z;
    float h1w[8];
#pragma unroll
    for (int j = 0; j < 8; ++j)
      h1w[j] = fmaxf(fmaf(dz, wnw1[16 + j], fmaf(dy, wnw1[8 + j], fmaf(dx, wnw1[j], wnb1[j]))), 0.f);
#pragma unroll
    for (int j = 0; j < 8; ++j) {
      float a = wnb2[j];
#pragma unroll
      for (int qq = 0; qq < 8; ++qq) a = fmaf(h1w[qq], wnw2[qq * 8 + j], a);
      s_wn[tid][j] = fmaxf(a, 0.f);
    }
  }
  int k2 = tid >> 4, i2 = tid & 15;
  int mg = idx2[(size_t)gid * 16 + k2];
  const float* src = &ptp[(size_t)((b << 12) + mg) * 128 + i2 * 8];
  *(float4*)&s_gc[k2][i2 * 8] = *(const float4*)&src[0];
  *(float4*)&s_gc[k2][i2 * 8 + 4] = *(const float4*)&src[4];
  __syncthreads();
  int ch = tid & 127, kg2 = tid >> 7;
  float r = 0.f;
#pragma unroll
  for (int jj = 0; jj < 8; ++jj) {
    int k = kg2 * 8 + jj;
    float4 wa = *(const float4*)&s_wn[k][0];
    float4 wb = *(const float4*)&s_wn[k][4];
    float wv = wnb3[ch];
    wv = fmaf(wa.x, wnw3[ch], wv);
    wv = fmaf(wa.y, wnw3[128 + ch], wv);
    wv = fmaf(wa.z, wnw3[256 + ch], wv);
    wv = fmaf(wa.w, wnw3[384 + ch], wv);
    wv = fmaf(wb.x, wnw3[512 + ch], wv);
    wv = fmaf(wb.y, wnw3[640 + ch], wv);
    wv = fmaf(wb.z, wnw3[768 + ch], wv);
    wv = fmaf(wb.w, wnw3[896 + ch], wv);
    wv = fmaxf(wv, 0.f);
    r = fmaf(wv, s_gc[k][ch], r);
  }
  s_red[kg2][ch] = r;
  __syncthreads();
  if (tid < 128)
    out0[(size_t)(b * 128 + tid) * NPTS + n] = s_red[0][tid] + s_red[1][tid];
}

extern "C" void kernel_launch(void* const* d_in, const int* in_sizes, int n_in,
                              void* d_out, int out_size, void* d_ws, size_t ws_size,
                              hipStream_t stream) {
  (void)in_sizes; (void)n_in; (void)out_size; (void)ws_size;
  const float* xyz1   = (const float*)d_in[0];
  const float* xyz2   = (const float*)d_in[1];
  const float* pts1   = (const float*)d_in[2];
  const float* pts2   = (const float*)d_in[3];
  const float* vel1   = (const float*)d_in[4];
  const float* w_xyz  = (const float*)d_in[8];
  const float* w_pts  = (const float*)d_in[10];
  const float* mlp_w1 = (const float*)d_in[11];
  const float* mlp_b1 = (const float*)d_in[12];
  const float* mlp_w2 = (const float*)d_in[13];
  const float* mlp_b2 = (const float*)d_in[14];
  const float* wn1_w1 = (const float*)d_in[15];
  const float* wn1_b1 = (const float*)d_in[16];
  const float* wn1_w2 = (const float*)d_in[17];
  const float* wn1_b2 = (const float*)d_in[18];
  const float* wn1_w3 = (const float*)d_in[19];
  const float* wn1_b3 = (const float*)d_in[20];
  const float* wn2_w1 = (const float*)d_in[21];
  const float* wn2_b1 = (const float*)d_in[22];
  const float* wn2_w2 = (const float*)d_in[23];
  const float* wn2_b2 = (const float*)d_in[24];
  const float* wn2_w3 = (const float*)d_in[25];
  const float* wn2_b3 = (const float*)d_in[26];

  char* ws = (char*)d_ws;
  size_t off = 0;
  float* pd   = (float*)(ws + off); off += (size_t)NQ * NSEG * 16 * 4;   // 8 MB
  int*   pi   = (int*)(ws + off);   off += (size_t)NQ * NSEG * 16 * 4;   // 8 MB
  float* f1   = (float*)(ws + off); off += (size_t)NQ * FPAD * 4;
  float* f2   = (float*)(ws + off); off += (size_t)NQ * FPAD * 4;
  float* n1   = (float*)(ws + off); off += (size_t)NQ * 4;
  float* p1t  = (float*)(ws + off); off += (size_t)NQ * DD * 4;
  float* p2t  = (float*)(ws + off); off += (size_t)NQ * DD * 4;
  float* x1t  = (float*)(ws + off); off += (size_t)NQ * 4 * 4;
  float* x2t  = (float*)(ws + off); off += (size_t)NQ * 4 * 4;
  int*   kidx = (int*)(ws + off);   off += (size_t)NQ * KNN * 4;
  float* ptp  = (float*)(ws + off); off += (size_t)NQ * 128 * 4;
  int*   idx2 = (int*)(ws + off);   off += (size_t)NQ * KNN * 4;
  float* v4   = (float*)(ws + off); off += (size_t)NQ * 4 * 4;

  float* out0 = (float*)d_out;
  float* outv = (float*)d_out + VOFF;

  k_prep<<<32, 256, 0, stream>>>(xyz1, xyz2, pts1, pts2, w_xyz, w_pts,
                                 f1, f2, n1, p1t, p2t, x1t, x2t);
  k_knn_pt<KC><<<dim3(32, NSEG), 256, 0, stream>>>(x1t, pd, pi);
  k_rigid<<<32, 256, 0, stream>>>(pd, pi, x1t, vel1, outv, v4);
  k_knnf<<<dim3(32, NSEG), 256, 0, stream>>>(f1, f2, n1, pd, pi);
  k_merge16<<<32, 256, 0, stream>>>(pd, pi, kidx);
  k_mlp<<<NQ, 256, 0, stream>>>(p1t, p2t, x1t, x2t, kidx,
                                mlp_w1, mlp_b1, mlp_w2, mlp_b2,
                                wn1_w1, wn1_b1, wn1_w2, wn1_b2, wn1_w3, wn1_b3, ptp);
  k_knn_pt<KNN><<<dim3(32, NSEG), 256, 0, stream>>>(v4, pd, pi);
  k_merge16<<<32, 256, 0, stream>>>(pd, pi, idx2);
  k_final<<<NQ, 256, 0, stream>>>(x1t, idx2, ptp,
                                  wn2_w1, wn2_b1, wn2_w2, wn2_b2, wn2_w3, wn2_b3, out0);
}

// Round 3
// 1638.212 us; speedup vs baseline: 1.0858x; 1.0858x over previous
//
#include <hip/hip_runtime.h>

#define NPTS 4096
#define NQ   8192      // B*N
#define DD   64
#define KNN  16
#define KC   8
#define NSEG 16
#define SEGLEN 256     // NPTS/NSEG (staged knn kernels)
#define FPAD 68        // 67 features + 1 pad (f2 pad slot holds n2; f1 pad = 0)
#define VOFF 1048576   // B*128*N, float offset of v_world in d_out

__device__ inline float leakyf(float x) { return x > 0.f ? x : 0.1f * x; }

template<int K>
__device__ inline void topk_ins(float (&dv)[K], int (&iv)[K], float d, int m) {
  if (d < dv[K-1]) {
    float vd = d; int vi = m;
#pragma unroll
    for (int s = 0; s < K; ++s) {
      if (vd < dv[s]) {
        float td = dv[s]; int ti = iv[s];
        dv[s] = vd; iv[s] = vi; vd = td; vi = ti;
      }
    }
  }
}

// ---------------- prep: transposes + weighted features + norms ----------------
__global__ __launch_bounds__(256) void k_prep(
    const float* __restrict__ xyz1, const float* __restrict__ xyz2,
    const float* __restrict__ pts1, const float* __restrict__ pts2,
    const float* __restrict__ w_xyz_p, const float* __restrict__ w_points_p,
    float* __restrict__ f1, float* __restrict__ f2,
    float* __restrict__ n1,
    float* __restrict__ p1t, float* __restrict__ p2t,
    float* __restrict__ x1t, float* __restrict__ x2t)
{
  int gid = blockIdx.x * 256 + threadIdx.x;   // 0..8191
  int b = gid >> 12, n = gid & (NPTS - 1);
  float wx = w_xyz_p[0], wp = w_points_p[0];
  {
    const float* xb = xyz1 + (size_t)b * 3 * NPTS;
    float x = xb[n], y = xb[NPTS + n], z = xb[2 * NPTS + n];
    float nrm2 = fmaf(z, z, fmaf(y, y, x * x));
    float4 xv; xv.x = x; xv.y = y; xv.z = z; xv.w = nrm2;
    *(float4*)&x1t[(size_t)gid * 4] = xv;
    float fx = wx * x, fy = wx * y, fz = wx * z;
    float acc = fmaf(fz, fz, fmaf(fy, fy, fx * fx));
    float* fr = f1 + (size_t)gid * FPAD;
    fr[0] = fx; fr[1] = fy; fr[2] = fz;
    const float* pb = pts1 + (size_t)b * DD * NPTS;
    float* pr = p1t + (size_t)gid * DD;
    for (int c = 0; c < DD; ++c) {
      float v = pb[(size_t)c * NPTS + n];
      pr[c] = v;
      float fv = wp * v;
      fr[3 + c] = fv;
      acc = fmaf(fv, fv, acc);
    }
    fr[67] = 0.f;           // query pad must stay 0 (so pad term adds 0 to dot)
    n1[gid] = acc;
  }
  {
    const float* xb = xyz2 + (size_t)b * 3 * NPTS;
    float x = xb[n], y = xb[NPTS + n], z = xb[2 * NPTS + n];
    float nrm2 = fmaf(z, z, fmaf(y, y, x * x));
    float4 xv; xv.x = x; xv.y = y; xv.z = z; xv.w = nrm2;
    *(float4*)&x2t[(size_t)gid * 4] = xv;
    float fx = wx * x, fy = wx * y, fz = wx * z;
    float acc = fmaf(fz, fz, fmaf(fy, fy, fx * fx));
    float* fr = f2 + (size_t)gid * FPAD;
    fr[0] = fx; fr[1] = fy; fr[2] = fz;
    const float* pb = pts2 + (size_t)b * DD * NPTS;
    float* pr = p2t + (size_t)gid * DD;
    for (int c = 0; c < DD; ++c) {
      float v = pb[(size_t)c * NPTS + n];
      pr[c] = v;
      float fv = wp * v;
      fr[3 + c] = fv;
      acc = fmaf(fv, fv, acc);
    }
    fr[67] = acc;           // candidate pad carries n2
  }
}

// ------- knn over [x,y,z,norm2] rows (LDS-staged, round-1 proven), partial per segment -------
template<int K>
__global__ __launch_bounds__(256) void k_knn_stg(
    const float* __restrict__ x4, float* __restrict__ pd, int* __restrict__ pi)
{
  __shared__ __align__(16) float4 sc[128];
  int seg = blockIdx.y;
  int Q = blockIdx.x * 256 + threadIdx.x;
  int b = Q >> 12;
  float4 q = *(const float4*)&x4[(size_t)Q * 4];
  float dv[K]; int iv[K];
#pragma unroll
  for (int s = 0; s < K; ++s) { dv[s] = 3.4e38f; iv[s] = 0; }
  int gbase = (b << 12) + seg * SEGLEN;
  for (int ch = 0; ch < SEGLEN / 128; ++ch) {
    __syncthreads();
    if (threadIdx.x < 128)
      sc[threadIdx.x] = *(const float4*)&x4[(size_t)(gbase + ch * 128 + threadIdx.x) * 4];
    __syncthreads();
    int m0 = seg * SEGLEN + ch * 128;
    for (int j = 0; j < 128; ++j) {
      float4 c = sc[j];
      float dot = fmaf(q.z, c.z, fmaf(q.y, c.y, q.x * c.x));
      float d = fmaxf(q.w + c.w - 2.f * dot, 0.f);
      topk_ins<K>(dv, iv, d, m0 + j);
    }
  }
  float* pdq = pd + ((size_t)Q * NSEG + seg) * 16;
  int* piq = pi + ((size_t)Q * NSEG + seg) * 16;
#pragma unroll
  for (int s = 0; s < K; ++s) { pdq[s] = dv[s]; piq[s] = iv[s]; }
}

// ---------------- merge K=8 + rigid velocity regression (+ padded v4 out) ----------------
__global__ __launch_bounds__(256) void k_rigid(
    const float* __restrict__ pd, const int* __restrict__ pi,
    const float* __restrict__ x4, const float* __restrict__ vel1,
    float* __restrict__ vout, float* __restrict__ v4out)
{
  int Q = blockIdx.x * 256 + threadIdx.x;
  int b = Q >> 12;
  float dv[KC]; int iv[KC];
#pragma unroll
  for (int s = 0; s < KC; ++s) { dv[s] = 3.4e38f; iv[s] = 0; }
  for (int s = 0; s < NSEG; ++s) {
    const float* pdq = pd + ((size_t)Q * NSEG + s) * 16;
    const int* piq = pi + ((size_t)Q * NSEG + s) * 16;
#pragma unroll
    for (int j = 0; j < KC; ++j) topk_ins<KC>(dv, iv, pdq[j], piq[j]);
  }
  int base = b << 12;
  double a00 = 0, a01 = 0, a02 = 0, a11 = 0, a12 = 0, a22 = 0;
  double r0 = 0, r1 = 0, r2 = 0;
#pragma unroll
  for (int t = 0; t < KC; ++t) {
    float4 c = *(const float4*)&x4[(size_t)(base + iv[t]) * 4];
    float nr = sqrtf(c.w);
    float ux = c.x / nr, uy = c.y / nr, uz = c.z / nr;
    float cv = vel1[base + iv[t]];
    double dx = ux, dy = uy, dz = uz, dvv = cv;
    a00 += dx * dx; a01 += dx * dy; a02 += dx * dz;
    a11 += dy * dy; a12 += dy * dz; a22 += dz * dz;
    r0 += dx * dvv; r1 += dy * dvv; r2 += dz * dvv;
  }
  a00 += 1e-6; a11 += 1e-6; a22 += 1e-6;
  double c00 = a11 * a22 - a12 * a12;
  double c01 = a02 * a12 - a01 * a22;
  double c02 = a01 * a12 - a02 * a11;
  double c11 = a00 * a22 - a02 * a02;
  double c12 = a02 * a01 - a00 * a12;
  double c22 = a00 * a11 - a01 * a01;
  double det = a00 * c00 + a01 * c01 + a02 * c02;
  double inv = 1.0 / det;
  float vx = (float)((c00 * r0 + c01 * r1 + c02 * r2) * inv);
  float vy = (float)((c01 * r0 + c11 * r1 + c12 * r2) * inv);
  float vz = (float)((c02 * r0 + c12 * r1 + c22 * r2) * inv);
  vout[(size_t)Q * 3 + 0] = vx;
  vout[(size_t)Q * 3 + 1] = vy;
  vout[(size_t)Q * 3 + 2] = vz;
  float4 v; v.x = vx; v.y = vy; v.z = vz;
  v.w = fmaf(vz, vz, fmaf(vy, vy, vx * vx));
  *(float4*)&v4out[(size_t)Q * 4] = v;
}

// ------- knnf as register-tiled distance-GEMM + fused partial top-k -------
// grid (128 q-tiles of 64, 4 candidate segments of 1024), block 256.
// Per chunk of 64 candidates: 17-step K loop, 4x4 outputs/thread.
// Writes 4 partial top-16s per (query,segment) -> 16 "psegs" merged by k_merge16.
__global__ __launch_bounds__(256) void k_knnf(
    const float* __restrict__ f1, const float* __restrict__ f2,
    const float* __restrict__ n1,
    float* __restrict__ pd, int* __restrict__ pi)
{
  __shared__ __align__(16) float4 sf1[64 * 17];   // [q][k4], linear-staged
  __shared__ __align__(16) float4 sf2[64 * 17];   // [c][k4], linear-staged
  __shared__ __align__(16) float  sD[64][68];     // [c][q], +4 pad
  int tid = threadIdx.x;
  int tx = tid & 15, ty = tid >> 4;               // c-group, q-group
  int blockq = blockIdx.x * 64;                   // global query base (gid)
  int b = blockq >> 12;
  int seg = blockIdx.y;
  int gbase = (b << 12) + seg * 1024;             // candidate row base (gid)
  const float4* f1v = (const float4*)f1;
  const float4* f2v = (const float4*)f2;
  {
    const float4* src = f1v + (size_t)blockq * 17;
    for (int idx = tid; idx < 1088; idx += 256) sf1[idx] = src[idx];
  }
  float n1q[4];
#pragma unroll
  for (int j = 0; j < 4; ++j) n1q[j] = n1[blockq + ty + 16 * j];
  float dv[16]; int iv[16];
#pragma unroll
  for (int s = 0; s < 16; ++s) { dv[s] = 3.4e38f; iv[s] = 0; }
  int p = tid >> 6, qq = tid & 63;
  for (int ch = 0; ch < 16; ++ch) {
    __syncthreads();      // prev chunk's sf2/sD reads complete
    {
      const float4* src = f2v + (size_t)(gbase + ch * 64) * 17;
      for (int idx = tid; idx < 1088; idx += 256) sf2[idx] = src[idx];
    }
    __syncthreads();      // sf2 ready
    float acc[4][4];
#pragma unroll
    for (int j = 0; j < 4; ++j)
#pragma unroll
      for (int i = 0; i < 4; ++i) acc[j][i] = 0.f;
#pragma unroll 4
    for (int k4 = 0; k4 < 16; ++k4) {
      float4 fq[4], fc[4];
#pragma unroll
      for (int j = 0; j < 4; ++j) fq[j] = sf1[(ty + 16 * j) * 17 + k4];
#pragma unroll
      for (int i = 0; i < 4; ++i) fc[i] = sf2[(tx + 16 * i) * 17 + k4];
#pragma unroll
      for (int j = 0; j < 4; ++j)
#pragma unroll
        for (int i = 0; i < 4; ++i) {
          acc[j][i] = fmaf(fq[j].x, fc[i].x, acc[j][i]);
          acc[j][i] = fmaf(fq[j].y, fc[i].y, acc[j][i]);
          acc[j][i] = fmaf(fq[j].z, fc[i].z, acc[j][i]);
          acc[j][i] = fmaf(fq[j].w, fc[i].w, acc[j][i]);
        }
    }
    float cw[4];
    {   // peeled k4 = 16: {f64,f65,f66, n2}; f1 pad .w = 0 so the .w FMA adds 0
      float4 fq[4], fc[4];
#pragma unroll
      for (int j = 0; j < 4; ++j) fq[j] = sf1[(ty + 16 * j) * 17 + 16];
#pragma unroll
      for (int i = 0; i < 4; ++i) { fc[i] = sf2[(tx + 16 * i) * 17 + 16]; cw[i] = fc[i].w; }
#pragma unroll
      for (int j = 0; j < 4; ++j)
#pragma unroll
        for (int i = 0; i < 4; ++i) {
          acc[j][i] = fmaf(fq[j].x, fc[i].x, acc[j][i]);
          acc[j][i] = fmaf(fq[j].y, fc[i].y, acc[j][i]);
          acc[j][i] = fmaf(fq[j].z, fc[i].z, acc[j][i]);
          acc[j][i] = fmaf(fq[j].w, fc[i].w, acc[j][i]);
        }
    }
#pragma unroll
    for (int j = 0; j < 4; ++j)
#pragma unroll
      for (int i = 0; i < 4; ++i) {
        float d = fmaxf(n1q[j] + cw[i] - 2.f * acc[j][i], 0.f);
        sD[tx + 16 * i][ty + 16 * j] = d;
      }
    __syncthreads();      // sD ready
    int mbase = seg * 1024 + ch * 64 + p * 16;
    for (int cl = 0; cl < 16; ++cl)
      topk_ins<16>(dv, iv, sD[p * 16 + cl][qq], mbase + cl);
  }
  int pseg = seg * 4 + p;
  float* pdq = pd + ((size_t)(blockq + qq) * NSEG + pseg) * 16;
  int* piq = pi + ((size_t)(blockq + qq) * NSEG + pseg) * 16;
#pragma unroll
  for (int s = 0; s < 16; ++s) { pdq[s] = dv[s]; piq[s] = iv[s]; }
}

// ---------------- merge K=16 → final indices ----------------
__global__ __launch_bounds__(256) void k_merge16(
    const float* __restrict__ pd, const int* __restrict__ pi, int* __restrict__ oidx)
{
  int Q = blockIdx.x * 256 + threadIdx.x;
  float dv[KNN]; int iv[KNN];
#pragma unroll
  for (int s = 0; s < KNN; ++s) { dv[s] = 3.4e38f; iv[s] = 0; }
  for (int s = 0; s < NSEG; ++s) {
    const float* pdq = pd + ((size_t)Q * NSEG + s) * 16;
    const int* piq = pi + ((size_t)Q * NSEG + s) * 16;
#pragma unroll
    for (int j = 0; j < KNN; ++j) topk_ins<KNN>(dv, iv, pdq[j], piq[j]);
  }
#pragma unroll
  for (int j = 0; j < KNN; ++j) oidx[(size_t)Q * KNN + j] = iv[j];
}

// ---------------- fused cost-volume MLP + weightnet1 + k-sum ----------------
__global__ __launch_bounds__(256) void k_mlp(
    const float* __restrict__ p1t, const float* __restrict__ p2t,
    const float* __restrict__ x1t, const float* __restrict__ x2t,
    const int* __restrict__ kidx,
    const float* __restrict__ W1, const float* __restrict__ B1v,
    const float* __restrict__ W2, const float* __restrict__ B2v,
    const float* __restrict__ wnw1, const float* __restrict__ wnb1,
    const float* __restrict__ wnw2, const float* __restrict__ wnb2,
    const float* __restrict__ wnw3, const float* __restrict__ wnb3,
    float* __restrict__ ptp)
{
  __shared__ __align__(16) float s_p1[64];
  __shared__ __align__(16) float s_g2t[64][20];
  __shared__ __align__(16) float s_dirt[3][20];
  __shared__ __align__(16) float s_h1t[128][20];
  __shared__ __align__(16) float s_wn[16][8];
  __shared__ __align__(16) float s_red[2][128];
  int gid = blockIdx.x, b = gid >> 12, tid = threadIdx.x;
  int ch = tid & 127, kh = tid >> 7, kb = kh * 8;

  if (tid < 16) ((float4*)s_p1)[tid] = *(const float4*)&p1t[(size_t)gid * 64 + tid * 4];
  int k_ld = tid >> 4, c_ld = (tid & 15) * 4;
  int m = kidx[(size_t)gid * 16 + k_ld];
  int grow = (b << 12) + m;
  float4 gv = *(const float4*)&p2t[(size_t)grow * 64 + c_ld];
  s_g2t[c_ld + 0][k_ld] = gv.x;
  s_g2t[c_ld + 1][k_ld] = gv.y;
  s_g2t[c_ld + 2][k_ld] = gv.z;
  s_g2t[c_ld + 3][k_ld] = gv.w;
  if ((tid & 15) == 0) {
    float4 c2 = *(const float4*)&x2t[(size_t)grow * 4];
    float4 c1 = *(const float4*)&x1t[(size_t)gid * 4];
    s_dirt[0][k_ld] = c2.x - c1.x;
    s_dirt[1][k_ld] = c2.y - c1.y;
    s_dirt[2][k_ld] = c2.z - c1.z;
  }
  __syncthreads();
  if (tid < 16) {
    float dx = s_dirt[0][tid], dy = s_dirt[1][tid], dz = s_dirt[2][tid];
    float h1w[8];
#pragma unroll
    for (int j = 0; j < 8; ++j)
      h1w[j] = fmaxf(fmaf(dz, wnw1[16 + j], fmaf(dy, wnw1[8 + j], fmaf(dx, wnw1[j], wnb1[j]))), 0.f);
#pragma unroll
    for (int j = 0; j < 8; ++j) {
      float a = wnb2[j];
#pragma unroll
      for (int qq = 0; qq < 8; ++qq) a = fmaf(h1w[qq], wnw2[qq * 8 + j], a);
      s_wn[tid][j] = fmaxf(a, 0.f);
    }
  }
  // layer1 p1-center part (same for all k)
  float pre = B1v[ch];
#pragma unroll
  for (int c4 = 0; c4 < 16; ++c4) {
    float4 p = ((float4*)s_p1)[c4];
    const float* wr = &W1[(size_t)c4 * 4 * 128 + ch];
    pre = fmaf(p.x, wr[0], pre);
    pre = fmaf(p.y, wr[128], pre);
    pre = fmaf(p.z, wr[256], pre);
    pre = fmaf(p.w, wr[384], pre);
  }
  float acc[8];
#pragma unroll
  for (int j = 0; j < 8; ++j) acc[j] = pre;
  for (int c = 0; c < 64; ++c) {
    float4 g0 = *(const float4*)&s_g2t[c][kb];
    float4 g1 = *(const float4*)&s_g2t[c][kb + 4];
    float w = W1[(size_t)(64 + c) * 128 + ch];
    acc[0] = fmaf(g0.x, w, acc[0]); acc[1] = fmaf(g0.y, w, acc[1]);
    acc[2] = fmaf(g0.z, w, acc[2]); acc[3] = fmaf(g0.w, w, acc[3]);
    acc[4] = fmaf(g1.x, w, acc[4]); acc[5] = fmaf(g1.y, w, acc[5]);
    acc[6] = fmaf(g1.z, w, acc[6]); acc[7] = fmaf(g1.w, w, acc[7]);
  }
#pragma unroll
  for (int jd = 0; jd < 3; ++jd) {
    float4 d0 = *(const float4*)&s_dirt[jd][kb];
    float4 d1 = *(const float4*)&s_dirt[jd][kb + 4];
    float w = W1[(size_t)(128 + jd) * 128 + ch];
    acc[0] = fmaf(d0.x, w, acc[0]); acc[1] = fmaf(d0.y, w, acc[1]);
    acc[2] = fmaf(d0.z, w, acc[2]); acc[3] = fmaf(d0.w, w, acc[3]);
    acc[4] = fmaf(d1.x, w, acc[4]); acc[5] = fmaf(d1.y, w, acc[5]);
    acc[6] = fmaf(d1.z, w, acc[6]); acc[7] = fmaf(d1.w, w, acc[7]);
  }
#pragma unroll
  for (int j = 0; j < 8; ++j) s_h1t[ch][kb + j] = leakyf(acc[j]);
  __syncthreads();
  float acc2[8];
  float b2 = B2v[ch];
#pragma unroll
  for (int j = 0; j < 8; ++j) acc2[j] = b2;
  for (int c = 0; c < 128; ++c) {
    float4 h0 = *(const float4*)&s_h1t[c][kb];
    float4 h1 = *(const float4*)&s_h1t[c][kb + 4];
    float w = W2[(size_t)c * 128 + ch];
    acc2[0] = fmaf(h0.x, w, acc2[0]); acc2[1] = fmaf(h0.y, w, acc2[1]);
    acc2[2] = fmaf(h0.z, w, acc2[2]); acc2[3] = fmaf(h0.w, w, acc2[3]);
    acc2[4] = fmaf(h1.x, w, acc2[4]); acc2[5] = fmaf(h1.y, w, acc2[5]);
    acc2[6] = fmaf(h1.z, w, acc2[6]); acc2[7] = fmaf(h1.w, w, acc2[7]);
  }
  float r = 0.f;
#pragma unroll
  for (int j = 0; j < 8; ++j) {
    float v = leakyf(acc2[j]);
    int k = kb + j;
    float4 wa = *(const float4*)&s_wn[k][0];
    float4 wb = *(const float4*)&s_wn[k][4];
    float wv = wnb3[ch];
    wv = fmaf(wa.x, wnw3[ch], wv);
    wv = fmaf(wa.y, wnw3[128 + ch], wv);
    wv = fmaf(wa.z, wnw3[256 + ch], wv);
    wv = fmaf(wa.w, wnw3[384 + ch], wv);
    wv = fmaf(wb.x, wnw3[512 + ch], wv);
    wv = fmaf(wb.y, wnw3[640 + ch], wv);
    wv = fmaf(wb.z, wnw3[768 + ch], wv);
    wv = fmaf(wb.w, wnw3[896 + ch], wv);
    wv = fmaxf(wv, 0.f);
    r = fmaf(wv, v, r);
  }
  s_red[kh][ch] = r;
  __syncthreads();
  if (tid < 128) ptp[(size_t)gid * 128 + tid] = s_red[0][tid] + s_red[1][tid];
}

// ---------------- final: weightnet2 + gather + k-sum + transpose store ----------------
__global__ __launch_bounds__(256) void k_final(
    const float* __restrict__ x1t, const int* __restrict__ idx2,
    const float* __restrict__ ptp,
    const float* __restrict__ wnw1, const float* __restrict__ wnb1,
    const float* __restrict__ wnw2, const float* __restrict__ wnb2,
    const float* __restrict__ wnw3, const float* __restrict__ wnb3,
    float* __restrict__ out0)
{
  __shared__ __align__(16) float s_gc[16][128];
  __shared__ __align__(16) float s_wn[16][8];
  __shared__ __align__(16) float s_red[2][128];
  int gid = blockIdx.x, b = gid >> 12, n = gid & (NPTS - 1);
  int tid = threadIdx.x;
  if (tid < 16) {
    int m = idx2[(size_t)gid * 16 + tid];
    float4 c2 = *(const float4*)&x1t[(size_t)((b << 12) + m) * 4];
    float4 c1 = *(const float4*)&x1t[(size_t)gid * 4];
    float dx = c2.x - c1.x, dy = c2.y - c1.y, dz = c2.z - c1.z;
    float h1w[8];
#pragma unroll
    for (int j = 0; j < 8; ++j)
      h1w[j] = fmaxf(fmaf(dz, wnw1[16 + j], fmaf(dy, wnw1[8 + j], fmaf(dx, wnw1[j], wnb1[j]))), 0.f);
#pragma unroll
    for (int j = 0; j < 8; ++j) {
      float a = wnb2[j];
#pragma unroll
      for (int qq = 0; qq < 8; ++qq) a = fmaf(h1w[qq], wnw2[qq * 8 + j], a);
      s_wn[tid][j] = fmaxf(a, 0.f);
    }
  }
  int k2 = tid >> 4, i2 = tid & 15;
  int mg = idx2[(size_t)gid * 16 + k2];
  const float* src = &ptp[(size_t)((b << 12) + mg) * 128 + i2 * 8];
  *(float4*)&s_gc[k2][i2 * 8] = *(const float4*)&src[0];
  *(float4*)&s_gc[k2][i2 * 8 + 4] = *(const float4*)&src[4];
  __syncthreads();
  int ch = tid & 127, kg2 = tid >> 7;
  float r = 0.f;
#pragma unroll
  for (int jj = 0; jj < 8; ++jj) {
    int k = kg2 * 8 + jj;
    float4 wa = *(const float4*)&s_wn[k][0];
    float4 wb = *(const float4*)&s_wn[k][4];
    float wv = wnb3[ch];
    wv = fmaf(wa.x, wnw3[ch], wv);
    wv = fmaf(wa.y, wnw3[128 + ch], wv);
    wv = fmaf(wa.z, wnw3[256 + ch], wv);
    wv = fmaf(wa.w, wnw3[384 + ch], wv);
    wv = fmaf(wb.x, wnw3[512 + ch], wv);
    wv = fmaf(wb.y, wnw3[640 + ch], wv);
    wv = fmaf(wb.z, wnw3[768 + ch], wv);
    wv = fmaf(wb.w, wnw3[896 + ch], wv);
    wv = fmaxf(wv, 0.f);
    r = fmaf(wv, s_gc[k][ch], r);
  }
  s_red[kg2][ch] = r;
  __syncthreads();
  if (tid < 128)
    out0[(size_t)(b * 128 + tid) * NPTS + n] = s_red[0][tid] + s_red[1][tid];
}

extern "C" void kernel_launch(void* const* d_in, const int* in_sizes, int n_in,
                              void* d_out, int out_size, void* d_ws, size_t ws_size,
                              hipStream_t stream) {
  (void)in_sizes; (void)n_in; (void)out_size; (void)ws_size;
  const float* xyz1   = (const float*)d_in[0];
  const float* xyz2   = (const float*)d_in[1];
  const float* pts1   = (const float*)d_in[2];
  const float* pts2   = (const float*)d_in[3];
  const float* vel1   = (const float*)d_in[4];
  const float* w_xyz  = (const float*)d_in[8];
  const float* w_pts  = (const float*)d_in[10];
  const float* mlp_w1 = (const float*)d_in[11];
  const float* mlp_b1 = (const float*)d_in[12];
  const float* mlp_w2 = (const float*)d_in[13];
  const float* mlp_b2 = (const float*)d_in[14];
  const float* wn1_w1 = (const float*)d_in[15];
  const float* wn1_b1 = (const float*)d_in[16];
  const float* wn1_w2 = (const float*)d_in[17];
  const float* wn1_b2 = (const float*)d_in[18];
  const float* wn1_w3 = (const float*)d_in[19];
  const float* wn1_b3 = (const float*)d_in[20];
  const float* wn2_w1 = (const float*)d_in[21];
  const float* wn2_b1 = (const float*)d_in[22];
  const float* wn2_w2 = (const float*)d_in[23];
  const float* wn2_b2 = (const float*)d_in[24];
  const float* wn2_w3 = (const float*)d_in[25];
  const float* wn2_b3 = (const float*)d_in[26];

  char* ws = (char*)d_ws;
  size_t off = 0;
  float* pd   = (float*)(ws + off); off += (size_t)NQ * NSEG * 16 * 4;   // 8 MB
  int*   pi   = (int*)(ws + off);   off += (size_t)NQ * NSEG * 16 * 4;   // 8 MB
  float* f1   = (float*)(ws + off); off += (size_t)NQ * FPAD * 4;
  float* f2   = (float*)(ws + off); off += (size_t)NQ * FPAD * 4;
  float* n1   = (float*)(ws + off); off += (size_t)NQ * 4;
  float* p1t  = (float*)(ws + off); off += (size_t)NQ * DD * 4;
  float* p2t  = (float*)(ws + off); off += (size_t)NQ * DD * 4;
  float* x1t  = (float*)(ws + off); off += (size_t)NQ * 4 * 4;
  float* x2t  = (float*)(ws + off); off += (size_t)NQ * 4 * 4;
  int*   kidx = (int*)(ws + off);   off += (size_t)NQ * KNN * 4;
  float* ptp  = (float*)(ws + off); off += (size_t)NQ * 128 * 4;
  int*   idx2 = (int*)(ws + off);   off += (size_t)NQ * KNN * 4;
  float* v4   = (float*)(ws + off); off += (size_t)NQ * 4 * 4;

  float* out0 = (float*)d_out;
  float* outv = (float*)d_out + VOFF;

  k_prep<<<32, 256, 0, stream>>>(xyz1, xyz2, pts1, pts2, w_xyz, w_pts,
                                 f1, f2, n1, p1t, p2t, x1t, x2t);
  k_knn_stg<KC><<<dim3(32, NSEG), 256, 0, stream>>>(x1t, pd, pi);
  k_rigid<<<32, 256, 0, stream>>>(pd, pi, x1t, vel1, outv, v4);
  k_knnf<<<dim3(128, 4), 256, 0, stream>>>(f1, f2, n1, pd, pi);
  k_merge16<<<32, 256, 0, stream>>>(pd, pi, kidx);
  k_mlp<<<NQ, 256, 0, stream>>>(p1t, p2t, x1t, x2t, kidx,
                                mlp_w1, mlp_b1, mlp_w2, mlp_b2,
                                wn1_w1, wn1_b1, wn1_w2, wn1_b2, wn1_w3, wn1_b3, ptp);
  k_knn_stg<KNN><<<dim3(32, NSEG), 256, 0, stream>>>(v4, pd, pi);
  k_merge16<<<32, 256, 0, stream>>>(pd, pi, idx2);
  k_final<<<NQ, 256, 0, stream>>>(x1t, idx2, ptp,
                                  wn2_w1, wn2_b1, wn2_w2, wn2_b2, wn2_w3, wn2_b3, out0);
}

// Round 4
// 1634.970 us; speedup vs baseline: 1.0879x; 1.0020x over previous
//
#include <hip/hip_runtime.h>

#define NPTS 4096
#define NQ   8192      // B*N
#define DD   64
#define KNN  16
#define KC   8
#define NSEG 16
#define SEGLEN 256     // NPTS/NSEG (staged knn kernels)
#define FPAD 68        // 67 features + 1 pad (f2 pad slot holds n2; f1 pad = 0)
#define VOFF 1048576   // B*128*N, float offset of v_world in d_out

#define ALWAYS_INLINE __attribute__((always_inline)) inline

__device__ ALWAYS_INLINE float leakyf(float x) { return x > 0.f ? x : 0.1f * x; }

// ALWAYS_INLINE is load-bearing: without it hipcc may keep this as a real call,
// forcing dv/iv (passed by reference) into scratch memory — every candidate then
// pays a serial chain of dependent scratch round-trips (~3000 cyc/candidate,
// observed as the invariant ~550µs knnf across three structural rewrites).
template<int K>
__device__ ALWAYS_INLINE void topk_ins(float (&dv)[K], int (&iv)[K], float d, int m) {
  if (d < dv[K-1]) {
    float vd = d; int vi = m;
#pragma unroll
    for (int s = 0; s < K; ++s) {
      if (vd < dv[s]) {
        float td = dv[s]; int ti = iv[s];
        dv[s] = vd; iv[s] = vi; vd = td; vi = ti;
      }
    }
  }
}

// ---------------- prep: transposes + weighted features + norms ----------------
__global__ __launch_bounds__(256) void k_prep(
    const float* __restrict__ xyz1, const float* __restrict__ xyz2,
    const float* __restrict__ pts1, const float* __restrict__ pts2,
    const float* __restrict__ w_xyz_p, const float* __restrict__ w_points_p,
    float* __restrict__ f1, float* __restrict__ f2,
    float* __restrict__ n1,
    float* __restrict__ p1t, float* __restrict__ p2t,
    float* __restrict__ x1t, float* __restrict__ x2t)
{
  int gid = blockIdx.x * 256 + threadIdx.x;   // 0..8191
  int b = gid >> 12, n = gid & (NPTS - 1);
  float wx = w_xyz_p[0], wp = w_points_p[0];
  {
    const float* xb = xyz1 + (size_t)b * 3 * NPTS;
    float x = xb[n], y = xb[NPTS + n], z = xb[2 * NPTS + n];
    float nrm2 = fmaf(z, z, fmaf(y, y, x * x));
    float4 xv; xv.x = x; xv.y = y; xv.z = z; xv.w = nrm2;
    *(float4*)&x1t[(size_t)gid * 4] = xv;
    float fx = wx * x, fy = wx * y, fz = wx * z;
    float acc = fmaf(fz, fz, fmaf(fy, fy, fx * fx));
    float* fr = f1 + (size_t)gid * FPAD;
    fr[0] = fx; fr[1] = fy; fr[2] = fz;
    const float* pb = pts1 + (size_t)b * DD * NPTS;
    float* pr = p1t + (size_t)gid * DD;
    for (int c = 0; c < DD; ++c) {
      float v = pb[(size_t)c * NPTS + n];
      pr[c] = v;
      float fv = wp * v;
      fr[3 + c] = fv;
      acc = fmaf(fv, fv, acc);
    }
    fr[67] = 0.f;           // query pad must stay 0 (so pad term adds 0 to dot)
    n1[gid] = acc;
  }
  {
    const float* xb = xyz2 + (size_t)b * 3 * NPTS;
    float x = xb[n], y = xb[NPTS + n], z = xb[2 * NPTS + n];
    float nrm2 = fmaf(z, z, fmaf(y, y, x * x));
    float4 xv; xv.x = x; xv.y = y; xv.z = z; xv.w = nrm2;
    *(float4*)&x2t[(size_t)gid * 4] = xv;
    float fx = wx * x, fy = wx * y, fz = wx * z;
    float acc = fmaf(fz, fz, fmaf(fy, fy, fx * fx));
    float* fr = f2 + (size_t)gid * FPAD;
    fr[0] = fx; fr[1] = fy; fr[2] = fz;
    const float* pb = pts2 + (size_t)b * DD * NPTS;
    float* pr = p2t + (size_t)gid * DD;
    for (int c = 0; c < DD; ++c) {
      float v = pb[(size_t)c * NPTS + n];
      pr[c] = v;
      float fv = wp * v;
      fr[3 + c] = fv;
      acc = fmaf(fv, fv, acc);
    }
    fr[67] = acc;           // candidate pad carries n2
  }
}

// ------- knn over [x,y,z,norm2] rows (LDS-staged), partial per segment -------
template<int K>
__global__ __launch_bounds__(256) void k_knn_stg(
    const float* __restrict__ x4, float* __restrict__ pd, int* __restrict__ pi)
{
  __shared__ __align__(16) float4 sc[128];
  int seg = blockIdx.y;
  int Q = blockIdx.x * 256 + threadIdx.x;
  int b = Q >> 12;
  float4 q = *(const float4*)&x4[(size_t)Q * 4];
  float dv[K]; int iv[K];
#pragma unroll
  for (int s = 0; s < K; ++s) { dv[s] = 3.4e38f; iv[s] = 0; }
  int gbase = (b << 12) + seg * SEGLEN;
  for (int ch = 0; ch < SEGLEN / 128; ++ch) {
    __syncthreads();
    if (threadIdx.x < 128)
      sc[threadIdx.x] = *(const float4*)&x4[(size_t)(gbase + ch * 128 + threadIdx.x) * 4];
    __syncthreads();
    int m0 = seg * SEGLEN + ch * 128;
    for (int j = 0; j < 128; ++j) {
      float4 c = sc[j];
      float dot = fmaf(q.z, c.z, fmaf(q.y, c.y, q.x * c.x));
      float d = fmaxf(q.w + c.w - 2.f * dot, 0.f);
      topk_ins<K>(dv, iv, d, m0 + j);
    }
  }
  float* pdq = pd + ((size_t)Q * NSEG + seg) * 16;
  int* piq = pi + ((size_t)Q * NSEG + seg) * 16;
#pragma unroll
  for (int s = 0; s < K; ++s) { pdq[s] = dv[s]; piq[s] = iv[s]; }
}

// ---------------- merge K=8 + rigid velocity regression (+ padded v4 out) ----------------
__global__ __launch_bounds__(256) void k_rigid(
    const float* __restrict__ pd, const int* __restrict__ pi,
    const float* __restrict__ x4, const float* __restrict__ vel1,
    float* __restrict__ vout, float* __restrict__ v4out)
{
  int Q = blockIdx.x * 256 + threadIdx.x;
  int b = Q >> 12;
  float dv[KC]; int iv[KC];
#pragma unroll
  for (int s = 0; s < KC; ++s) { dv[s] = 3.4e38f; iv[s] = 0; }
  for (int s = 0; s < NSEG; ++s) {
    const float* pdq = pd + ((size_t)Q * NSEG + s) * 16;
    const int* piq = pi + ((size_t)Q * NSEG + s) * 16;
#pragma unroll
    for (int j = 0; j < KC; ++j) topk_ins<KC>(dv, iv, pdq[j], piq[j]);
  }
  int base = b << 12;
  double a00 = 0, a01 = 0, a02 = 0, a11 = 0, a12 = 0, a22 = 0;
  double r0 = 0, r1 = 0, r2 = 0;
#pragma unroll
  for (int t = 0; t < KC; ++t) {
    float4 c = *(const float4*)&x4[(size_t)(base + iv[t]) * 4];
    float nr = sqrtf(c.w);
    float ux = c.x / nr, uy = c.y / nr, uz = c.z / nr;
    float cv = vel1[base + iv[t]];
    double dx = ux, dy = uy, dz = uz, dvv = cv;
    a00 += dx * dx; a01 += dx * dy; a02 += dx * dz;
    a11 += dy * dy; a12 += dy * dz; a22 += dz * dz;
    r0 += dx * dvv; r1 += dy * dvv; r2 += dz * dvv;
  }
  a00 += 1e-6; a11 += 1e-6; a22 += 1e-6;
  double c00 = a11 * a22 - a12 * a12;
  double c01 = a02 * a12 - a01 * a22;
  double c02 = a01 * a12 - a02 * a11;
  double c11 = a00 * a22 - a02 * a02;
  double c12 = a02 * a01 - a00 * a12;
  double c22 = a00 * a11 - a01 * a01;
  double det = a00 * c00 + a01 * c01 + a02 * c02;
  double inv = 1.0 / det;
  float vx = (float)((c00 * r0 + c01 * r1 + c02 * r2) * inv);
  float vy = (float)((c01 * r0 + c11 * r1 + c12 * r2) * inv);
  float vz = (float)((c02 * r0 + c12 * r1 + c22 * r2) * inv);
  vout[(size_t)Q * 3 + 0] = vx;
  vout[(size_t)Q * 3 + 1] = vy;
  vout[(size_t)Q * 3 + 2] = vz;
  float4 v; v.x = vx; v.y = vy; v.z = vz;
  v.w = fmaf(vz, vz, fmaf(vy, vy, vx * vx));
  *(float4*)&v4out[(size_t)Q * 4] = v;
}

// ------- knnf as register-tiled distance-GEMM + fused partial top-k -------
__global__ __launch_bounds__(256) void k_knnf(
    const float* __restrict__ f1, const float* __restrict__ f2,
    const float* __restrict__ n1,
    float* __restrict__ pd, int* __restrict__ pi)
{
  __shared__ __align__(16) float4 sf1[64 * 17];   // [q][k4], linear-staged
  __shared__ __align__(16) float4 sf2[64 * 17];   // [c][k4], linear-staged
  __shared__ __align__(16) float  sD[64][68];     // [c][q], +4 pad
  int tid = threadIdx.x;
  int tx = tid & 15, ty = tid >> 4;               // c-group, q-group
  int blockq = blockIdx.x * 64;                   // global query base (gid)
  int b = blockq >> 12;
  int seg = blockIdx.y;
  int gbase = (b << 12) + seg * 1024;             // candidate row base (gid)
  const float4* f1v = (const float4*)f1;
  const float4* f2v = (const float4*)f2;
  {
    const float4* src = f1v + (size_t)blockq * 17;
    for (int idx = tid; idx < 1088; idx += 256) sf1[idx] = src[idx];
  }
  float n1q[4];
#pragma unroll
  for (int j = 0; j < 4; ++j) n1q[j] = n1[blockq + ty + 16 * j];
  float dv[16]; int iv[16];
#pragma unroll
  for (int s = 0; s < 16; ++s) { dv[s] = 3.4e38f; iv[s] = 0; }
  int p = tid >> 6, qq = tid & 63;
  for (int ch = 0; ch < 16; ++ch) {
    __syncthreads();      // prev chunk's sf2/sD reads complete
    {
      const float4* src = f2v + (size_t)(gbase + ch * 64) * 17;
      for (int idx = tid; idx < 1088; idx += 256) sf2[idx] = src[idx];
    }
    __syncthreads();      // sf2 ready
    float acc[4][4];
#pragma unroll
    for (int j = 0; j < 4; ++j)
#pragma unroll
      for (int i = 0; i < 4; ++i) acc[j][i] = 0.f;
#pragma unroll 4
    for (int k4 = 0; k4 < 16; ++k4) {
      float4 fq[4], fc[4];
#pragma unroll
      for (int j = 0; j < 4; ++j) fq[j] = sf1[(ty + 16 * j) * 17 + k4];
#pragma unroll
      for (int i = 0; i < 4; ++i) fc[i] = sf2[(tx + 16 * i) * 17 + k4];
#pragma unroll
      for (int j = 0; j < 4; ++j)
#pragma unroll
        for (int i = 0; i < 4; ++i) {
          acc[j][i] = fmaf(fq[j].x, fc[i].x, acc[j][i]);
          acc[j][i] = fmaf(fq[j].y, fc[i].y, acc[j][i]);
          acc[j][i] = fmaf(fq[j].z, fc[i].z, acc[j][i]);
          acc[j][i] = fmaf(fq[j].w, fc[i].w, acc[j][i]);
        }
    }
    float cw[4];
    {   // peeled k4 = 16: {f64,f65,f66, n2}; f1 pad .w = 0 so the .w FMA adds 0
      float4 fq[4], fc[4];
#pragma unroll
      for (int j = 0; j < 4; ++j) fq[j] = sf1[(ty + 16 * j) * 17 + 16];
#pragma unroll
      for (int i = 0; i < 4; ++i) { fc[i] = sf2[(tx + 16 * i) * 17 + 16]; cw[i] = fc[i].w; }
#pragma unroll
      for (int j = 0; j < 4; ++j)
#pragma unroll
        for (int i = 0; i < 4; ++i) {
          acc[j][i] = fmaf(fq[j].x, fc[i].x, acc[j][i]);
          acc[j][i] = fmaf(fq[j].y, fc[i].y, acc[j][i]);
          acc[j][i] = fmaf(fq[j].z, fc[i].z, acc[j][i]);
          acc[j][i] = fmaf(fq[j].w, fc[i].w, acc[j][i]);
        }
    }
#pragma unroll
    for (int j = 0; j < 4; ++j)
#pragma unroll
      for (int i = 0; i < 4; ++i) {
        float d = fmaxf(n1q[j] + cw[i] - 2.f * acc[j][i], 0.f);
        sD[tx + 16 * i][ty + 16 * j] = d;
      }
    __syncthreads();      // sD ready
    int mbase = seg * 1024 + ch * 64 + p * 16;
    for (int cl = 0; cl < 16; ++cl)
      topk_ins<16>(dv, iv, sD[p * 16 + cl][qq], mbase + cl);
  }
  int pseg = seg * 4 + p;
  float* pdq = pd + ((size_t)(blockq + qq) * NSEG + pseg) * 16;
  int* piq = pi + ((size_t)(blockq + qq) * NSEG + pseg) * 16;
#pragma unroll
  for (int s = 0; s < 16; ++s) { pdq[s] = dv[s]; piq[s] = iv[s]; }
}

// ---------------- merge K=16 → final indices ----------------
__global__ __launch_bounds__(256) void k_merge16(
    const float* __restrict__ pd, const int* __restrict__ pi, int* __restrict__ oidx)
{
  int Q = blockIdx.x * 256 + threadIdx.x;
  float dv[KNN]; int iv[KNN];
#pragma unroll
  for (int s = 0; s < KNN; ++s) { dv[s] = 3.4e38f; iv[s] = 0; }
  for (int s = 0; s < NSEG; ++s) {
    const float* pdq = pd + ((size_t)Q * NSEG + s) * 16;
    const int* piq = pi + ((size_t)Q * NSEG + s) * 16;
#pragma unroll
    for (int j = 0; j < KNN; ++j) topk_ins<KNN>(dv, iv, pdq[j], piq[j]);
  }
#pragma unroll
  for (int j = 0; j < KNN; ++j) oidx[(size_t)Q * KNN + j] = iv[j];
}

// ---------------- fused cost-volume MLP + weightnet1 + k-sum ----------------
__global__ __launch_bounds__(256) void k_mlp(
    const float* __restrict__ p1t, const float* __restrict__ p2t,
    const float* __restrict__ x1t, const float* __restrict__ x2t,
    const int* __restrict__ kidx,
    const float* __restrict__ W1, const float* __restrict__ B1v,
    const float* __restrict__ W2, const float* __restrict__ B2v,
    const float* __restrict__ wnw1, const float* __restrict__ wnb1,
    const float* __restrict__ wnw2, const float* __restrict__ wnb2,
    const float* __restrict__ wnw3, const float* __restrict__ wnb3,
    float* __restrict__ ptp)
{
  __shared__ __align__(16) float s_p1[64];
  __shared__ __align__(16) float s_g2t[64][20];
  __shared__ __align__(16) float s_dirt[3][20];
  __shared__ __align__(16) float s_h1t[128][20];
  __shared__ __align__(16) float s_wn[16][8];
  __shared__ __align__(16) float s_red[2][128];
  int gid = blockIdx.x, b = gid >> 12, tid = threadIdx.x;
  int ch = tid & 127, kh = tid >> 7, kb = kh * 8;

  if (tid < 16) ((float4*)s_p1)[tid] = *(const float4*)&p1t[(size_t)gid * 64 + tid * 4];
  int k_ld = tid >> 4, c_ld = (tid & 15) * 4;
  int m = kidx[(size_t)gid * 16 + k_ld];
  int grow = (b << 12) + m;
  float4 gv = *(const float4*)&p2t[(size_t)grow * 64 + c_ld];
  s_g2t[c_ld + 0][k_ld] = gv.x;
  s_g2t[c_ld + 1][k_ld] = gv.y;
  s_g2t[c_ld + 2][k_ld] = gv.z;
  s_g2t[c_ld + 3][k_ld] = gv.w;
  if ((tid & 15) == 0) {
    float4 c2 = *(const float4*)&x2t[(size_t)grow * 4];
    float4 c1 = *(const float4*)&x1t[(size_t)gid * 4];
    s_dirt[0][k_ld] = c2.x - c1.x;
    s_dirt[1][k_ld] = c2.y - c1.y;
    s_dirt[2][k_ld] = c2.z - c1.z;
  }
  __syncthreads();
  if (tid < 16) {
    float dx = s_dirt[0][tid], dy = s_dirt[1][tid], dz = s_dirt[2][tid];
    float h1w[8];
#pragma unroll
    for (int j = 0; j < 8; ++j)
      h1w[j] = fmaxf(fmaf(dz, wnw1[16 + j], fmaf(dy, wnw1[8 + j], fmaf(dx, wnw1[j], wnb1[j]))), 0.f);
#pragma unroll
    for (int j = 0; j < 8; ++j) {
      float a = wnb2[j];
#pragma unroll
      for (int qq = 0; qq < 8; ++qq) a = fmaf(h1w[qq], wnw2[qq * 8 + j], a);
      s_wn[tid][j] = fmaxf(a, 0.f);
    }
  }
  // layer1 p1-center part (same for all k)
  float pre = B1v[ch];
#pragma unroll
  for (int c4 = 0; c4 < 16; ++c4) {
    float4 p = ((float4*)s_p1)[c4];
    const float* wr = &W1[(size_t)c4 * 4 * 128 + ch];
    pre = fmaf(p.x, wr[0], pre);
    pre = fmaf(p.y, wr[128], pre);
    pre = fmaf(p.z, wr[256], pre);
    pre = fmaf(p.w, wr[384], pre);
  }
  float acc[8];
#pragma unroll
  for (int j = 0; j < 8; ++j) acc[j] = pre;
  for (int c = 0; c < 64; ++c) {
    float4 g0 = *(const float4*)&s_g2t[c][kb];
    float4 g1 = *(const float4*)&s_g2t[c][kb + 4];
    float w = W1[(size_t)(64 + c) * 128 + ch];
    acc[0] = fmaf(g0.x, w, acc[0]); acc[1] = fmaf(g0.y, w, acc[1]);
    acc[2] = fmaf(g0.z, w, acc[2]); acc[3] = fmaf(g0.w, w, acc[3]);
    acc[4] = fmaf(g1.x, w, acc[4]); acc[5] = fmaf(g1.y, w, acc[5]);
    acc[6] = fmaf(g1.z, w, acc[6]); acc[7] = fmaf(g1.w, w, acc[7]);
  }
#pragma unroll
  for (int jd = 0; jd < 3; ++jd) {
    float4 d0 = *(const float4*)&s_dirt[jd][kb];
    float4 d1 = *(const float4*)&s_dirt[jd][kb + 4];
    float w = W1[(size_t)(128 + jd) * 128 + ch];
    acc[0] = fmaf(d0.x, w, acc[0]); acc[1] = fmaf(d0.y, w, acc[1]);
    acc[2] = fmaf(d0.z, w, acc[2]); acc[3] = fmaf(d0.w, w, acc[3]);
    acc[4] = fmaf(d1.x, w, acc[4]); acc[5] = fmaf(d1.y, w, acc[5]);
    acc[6] = fmaf(d1.z, w, acc[6]); acc[7] = fmaf(d1.w, w, acc[7]);
  }
#pragma unroll
  for (int j = 0; j < 8; ++j) s_h1t[ch][kb + j] = leakyf(acc[j]);
  __syncthreads();
  float acc2[8];
  float b2 = B2v[ch];
#pragma unroll
  for (int j = 0; j < 8; ++j) acc2[j] = b2;
  for (int c = 0; c < 128; ++c) {
    float4 h0 = *(const float4*)&s_h1t[c][kb];
    float4 h1 = *(const float4*)&s_h1t[c][kb + 4];
    float w = W2[(size_t)c * 128 + ch];
    acc2[0] = fmaf(h0.x, w, acc2[0]); acc2[1] = fmaf(h0.y, w, acc2[1]);
    acc2[2] = fmaf(h0.z, w, acc2[2]); acc2[3] = fmaf(h0.w, w, acc2[3]);
    acc2[4] = fmaf(h1.x, w, acc2[4]); acc2[5] = fmaf(h1.y, w, acc2[5]);
    acc2[6] = fmaf(h1.z, w, acc2[6]); acc2[7] = fmaf(h1.w, w, acc2[7]);
  }
  float r = 0.f;
#pragma unroll
  for (int j = 0; j < 8; ++j) {
    float v = leakyf(acc2[j]);
    int k = kb + j;
    float4 wa = *(const float4*)&s_wn[k][0];
    float4 wb = *(const float4*)&s_wn[k][4];
    float wv = wnb3[ch];
    wv = fmaf(wa.x, wnw3[ch], wv);
    wv = fmaf(wa.y, wnw3[128 + ch], wv);
    wv = fmaf(wa.z, wnw3[256 + ch], wv);
    wv = fmaf(wa.w, wnw3[384 + ch], wv);
    wv = fmaf(wb.x, wnw3[512 + ch], wv);
    wv = fmaf(wb.y, wnw3[640 + ch], wv);
    wv = fmaf(wb.z, wnw3[768 + ch], wv);
    wv = fmaf(wb.w, wnw3[896 + ch], wv);
    wv = fmaxf(wv, 0.f);
    r = fmaf(wv, v, r);
  }
  s_red[kh][ch] = r;
  __syncthreads();
  if (tid < 128) ptp[(size_t)gid * 128 + tid] = s_red[0][tid] + s_red[1][tid];
}

// ---------------- final: weightnet2 + gather + k-sum + transpose store ----------------
__global__ __launch_bounds__(256) void k_final(
    const float* __restrict__ x1t, const int* __restrict__ idx2,
    const float* __restrict__ ptp,
    const float* __restrict__ wnw1, const float* __restrict__ wnb1,
    const float* __restrict__ wnw2, const float* __restrict__ wnb2,
    const float* __restrict__ wnw3, const float* __restrict__ wnb3,
    float* __restrict__ out0)
{
  __shared__ __align__(16) float s_gc[16][128];
  __shared__ __align__(16) float s_wn[16][8];
  __shared__ __align__(16) float s_red[2][128];
  int gid = blockIdx.x, b = gid >> 12, n = gid & (NPTS - 1);
  int tid = threadIdx.x;
  if (tid < 16) {
    int m = idx2[(size_t)gid * 16 + tid];
    float4 c2 = *(const float4*)&x1t[(size_t)((b << 12) + m) * 4];
    float4 c1 = *(const float4*)&x1t[(size_t)gid * 4];
    float dx = c2.x - c1.x, dy = c2.y - c1.y, dz = c2.z - c1.z;
    float h1w[8];
#pragma unroll
    for (int j = 0; j < 8; ++j)
      h1w[j] = fmaxf(fmaf(dz, wnw1[16 + j], fmaf(dy, wnw1[8 + j], fmaf(dx, wnw1[j], wnb1[j]))), 0.f);
#pragma unroll
    for (int j = 0; j < 8; ++j) {
      float a = wnb2[j];
#pragma unroll
      for (int qq = 0; qq < 8; ++qq) a = fmaf(h1w[qq], wnw2[qq * 8 + j], a);
      s_wn[tid][j] = fmaxf(a, 0.f);
    }
  }
  int k2 = tid >> 4, i2 = tid & 15;
  int mg = idx2[(size_t)gid * 16 + k2];
  const float* src = &ptp[(size_t)((b << 12) + mg) * 128 + i2 * 8];
  *(float4*)&s_gc[k2][i2 * 8] = *(const float4*)&src[0];
  *(float4*)&s_gc[k2][i2 * 8 + 4] = *(const float4*)&src[4];
  __syncthreads();
  int ch = tid & 127, kg2 = tid >> 7;
  float r = 0.f;
#pragma unroll
  for (int jj = 0; jj < 8; ++jj) {
    int k = kg2 * 8 + jj;
    float4 wa = *(const float4*)&s_wn[k][0];
    float4 wb = *(const float4*)&s_wn[k][4];
    float wv = wnb3[ch];
    wv = fmaf(wa.x, wnw3[ch], wv);
    wv = fmaf(wa.y, wnw3[128 + ch], wv);
    wv = fmaf(wa.z, wnw3[256 + ch], wv);
    wv = fmaf(wa.w, wnw3[384 + ch], wv);
    wv = fmaf(wb.x, wnw3[512 + ch], wv);
    wv = fmaf(wb.y, wnw3[640 + ch], wv);
    wv = fmaf(wb.z, wnw3[768 + ch], wv);
    wv = fmaf(wb.w, wnw3[896 + ch], wv);
    wv = fmaxf(wv, 0.f);
    r = fmaf(wv, s_gc[k][ch], r);
  }
  s_red[kg2][ch] = r;
  __syncthreads();
  if (tid < 128)
    out0[(size_t)(b * 128 + tid) * NPTS + n] = s_red[0][tid] + s_red[1][tid];
}

extern "C" void kernel_launch(void* const* d_in, const int* in_sizes, int n_in,
                              void* d_out, int out_size, void* d_ws, size_t ws_size,
                              hipStream_t stream) {
  (void)in_sizes; (void)n_in; (void)out_size; (void)ws_size;
  const float* xyz1   = (const float*)d_in[0];
  const float* xyz2   = (const float*)d_in[1];
  const float* pts1   = (const float*)d_in[2];
  const float* pts2   = (const float*)d_in[3];
  const float* vel1   = (const float*)d_in[4];
  const float* w_xyz  = (const float*)d_in[8];
  const float* w_pts  = (const float*)d_in[10];
  const float* mlp_w1 = (const float*)d_in[11];
  const float* mlp_b1 = (const float*)d_in[12];
  const float* mlp_w2 = (const float*)d_in[13];
  const float* mlp_b2 = (const float*)d_in[14];
  const float* wn1_w1 = (const float*)d_in[15];
  const float* wn1_b1 = (const float*)d_in[16];
  const float* wn1_w2 = (const float*)d_in[17];
  const float* wn1_b2 = (const float*)d_in[18];
  const float* wn1_w3 = (const float*)d_in[19];
  const float* wn1_b3 = (const float*)d_in[20];
  const float* wn2_w1 = (const float*)d_in[21];
  const float* wn2_b1 = (const float*)d_in[22];
  const float* wn2_w2 = (const float*)d_in[23];
  const float* wn2_b2 = (const float*)d_in[24];
  const float* wn2_w3 = (const float*)d_in[25];
  const float* wn2_b3 = (const float*)d_in[26];

  char* ws = (char*)d_ws;
  size_t off = 0;
  float* pd   = (float*)(ws + off); off += (size_t)NQ * NSEG * 16 * 4;   // 8 MB
  int*   pi   = (int*)(ws + off);   off += (size_t)NQ * NSEG * 16 * 4;   // 8 MB
  float* f1   = (float*)(ws + off); off += (size_t)NQ * FPAD * 4;
  float* f2   = (float*)(ws + off); off += (size_t)NQ * FPAD * 4;
  float* n1   = (float*)(ws + off); off += (size_t)NQ * 4;
  float* p1t  = (float*)(ws + off); off += (size_t)NQ * DD * 4;
  float* p2t  = (float*)(ws + off); off += (size_t)NQ * DD * 4;
  float* x1t  = (float*)(ws + off); off += (size_t)NQ * 4 * 4;
  float* x2t  = (float*)(ws + off); off += (size_t)NQ * 4 * 4;
  int*   kidx = (int*)(ws + off);   off += (size_t)NQ * KNN * 4;
  float* ptp  = (float*)(ws + off); off += (size_t)NQ * 128 * 4;
  int*   idx2 = (int*)(ws + off);   off += (size_t)NQ * KNN * 4;
  float* v4   = (float*)(ws + off); off += (size_t)NQ * 4 * 4;

  float* out0 = (float*)d_out;
  float* outv = (float*)d_out + VOFF;

  k_prep<<<32, 256, 0, stream>>>(xyz1, xyz2, pts1, pts2, w_xyz, w_pts,
                                 f1, f2, n1, p1t, p2t, x1t, x2t);
  k_knn_stg<KC><<<dim3(32, NSEG), 256, 0, stream>>>(x1t, pd, pi);
  k_rigid<<<32, 256, 0, stream>>>(pd, pi, x1t, vel1, outv, v4);
  k_knnf<<<dim3(128, 4), 256, 0, stream>>>(f1, f2, n1, pd, pi);
  k_merge16<<<32, 256, 0, stream>>>(pd, pi, kidx);
  k_mlp<<<NQ, 256, 0, stream>>>(p1t, p2t, x1t, x2t, kidx,
                                mlp_w1, mlp_b1, mlp_w2, mlp_b2,
                                wn1_w1, wn1_b1, wn1_w2, wn1_b2, wn1_w3, wn1_b3, ptp);
  k_knn_stg<KNN><<<dim3(32, NSEG), 256, 0, stream>>>(v4, pd, pi);
  k_merge16<<<32, 256, 0, stream>>>(pd, pi, idx2);
  k_final<<<NQ, 256, 0, stream>>>(x1t, idx2, ptp,
                                  wn2_w1, wn2_b1, wn2_w2, wn2_b2, wn2_w3, wn2_b3, out0);
}

// Round 5
// 771.238 us; speedup vs baseline: 2.3064x; 2.1199x over previous
//
#include <hip/hip_runtime.h>

#define NPTS 4096
#define NQ   8192      // B*N
#define DD   64
#define KNN  16
#define KC   8
#define NSEG 16
#define SEGLEN 256     // NPTS/NSEG (staged knn kernels)
#define FPAD 68        // 67 features + 1 pad (f2 pad slot holds n2; f1 pad = 0)
#define VOFF 1048576   // B*128*N, float offset of v_world in d_out

#define ALWAYS_INLINE __attribute__((always_inline)) inline

__device__ ALWAYS_INLINE float leakyf(float x) { return x > 0.f ? x : 0.1f * x; }

// ---- top-k state as NAMED SCALARS (never arrays!) ----
// Array-based dv[K]/iv[K] were scratch-allocated by hipcc in rounds 1-4
// (VGPR_Count 68-80 with ~32 array slots unaccounted; time insensitive to
// 16x work changes). Named scalars are guaranteed register-allocatable.
#define TK8_FOREACH(M)  M(0) M(1) M(2) M(3) M(4) M(5) M(6) M(7)
#define TK16_FOREACH(M) M(0) M(1) M(2) M(3) M(4) M(5) M(6) M(7) \
                        M(8) M(9) M(10) M(11) M(12) M(13) M(14) M(15)

#define TK_DECL1(i) float tkd##i = 3.4e38f; int tki##i = 0;
#define TK_STEP1(i) { bool c = vd < tkd##i; float t_ = tkd##i; int u_ = tki##i; \
                      tkd##i = c ? vd : tkd##i; tki##i = c ? vi : tki##i; \
                      vd = c ? t_ : vd; vi = c ? u_ : vi; }
#define TK_STORE1(i) pdq[i] = tkd##i; piq[i] = tki##i;

#define TK8_DECL  TK8_FOREACH(TK_DECL1)
#define TK16_DECL TK16_FOREACH(TK_DECL1)
#define TK8_INS(dexp, mexp)  { float vd = (dexp); int vi = (mexp); \
                               if (vd < tkd7)  { TK8_FOREACH(TK_STEP1) } }
#define TK16_INS(dexp, mexp) { float vd = (dexp); int vi = (mexp); \
                               if (vd < tkd15) { TK16_FOREACH(TK_STEP1) } }
#define TK8_STORE  TK8_FOREACH(TK_STORE1)
#define TK16_STORE TK16_FOREACH(TK_STORE1)

// ---------------- prep: transposes + weighted features + norms ----------------
__global__ __launch_bounds__(256) void k_prep(
    const float* __restrict__ xyz1, const float* __restrict__ xyz2,
    const float* __restrict__ pts1, const float* __restrict__ pts2,
    const float* __restrict__ w_xyz_p, const float* __restrict__ w_points_p,
    float* __restrict__ f1, float* __restrict__ f2,
    float* __restrict__ n1,
    float* __restrict__ p1t, float* __restrict__ p2t,
    float* __restrict__ x1t, float* __restrict__ x2t)
{
  int gid = blockIdx.x * 256 + threadIdx.x;   // 0..8191
  int b = gid >> 12, n = gid & (NPTS - 1);
  float wx = w_xyz_p[0], wp = w_points_p[0];
  {
    const float* xb = xyz1 + (size_t)b * 3 * NPTS;
    float x = xb[n], y = xb[NPTS + n], z = xb[2 * NPTS + n];
    float nrm2 = fmaf(z, z, fmaf(y, y, x * x));
    float4 xv; xv.x = x; xv.y = y; xv.z = z; xv.w = nrm2;
    *(float4*)&x1t[(size_t)gid * 4] = xv;
    float fx = wx * x, fy = wx * y, fz = wx * z;
    float acc = fmaf(fz, fz, fmaf(fy, fy, fx * fx));
    float* fr = f1 + (size_t)gid * FPAD;
    fr[0] = fx; fr[1] = fy; fr[2] = fz;
    const float* pb = pts1 + (size_t)b * DD * NPTS;
    float* pr = p1t + (size_t)gid * DD;
    for (int c = 0; c < DD; ++c) {
      float v = pb[(size_t)c * NPTS + n];
      pr[c] = v;
      float fv = wp * v;
      fr[3 + c] = fv;
      acc = fmaf(fv, fv, acc);
    }
    fr[67] = 0.f;           // query pad must stay 0 (so pad term adds 0 to dot)
    n1[gid] = acc;
  }
  {
    const float* xb = xyz2 + (size_t)b * 3 * NPTS;
    float x = xb[n], y = xb[NPTS + n], z = xb[2 * NPTS + n];
    float nrm2 = fmaf(z, z, fmaf(y, y, x * x));
    float4 xv; xv.x = x; xv.y = y; xv.z = z; xv.w = nrm2;
    *(float4*)&x2t[(size_t)gid * 4] = xv;
    float fx = wx * x, fy = wx * y, fz = wx * z;
    float acc = fmaf(fz, fz, fmaf(fy, fy, fx * fx));
    float* fr = f2 + (size_t)gid * FPAD;
    fr[0] = fx; fr[1] = fy; fr[2] = fz;
    const float* pb = pts2 + (size_t)b * DD * NPTS;
    float* pr = p2t + (size_t)gid * DD;
    for (int c = 0; c < DD; ++c) {
      float v = pb[(size_t)c * NPTS + n];
      pr[c] = v;
      float fv = wp * v;
      fr[3 + c] = fv;
      acc = fmaf(fv, fv, acc);
    }
    fr[67] = acc;           // candidate pad carries n2
  }
}

// ------- knn over xyz1 [x,y,z,norm2] rows (LDS-staged), K=8, partial per segment -------
__global__ __launch_bounds__(256) void k_knn3(
    const float* __restrict__ x4, float* __restrict__ pd, int* __restrict__ pi)
{
  __shared__ __align__(16) float4 sc[128];
  int seg = blockIdx.y;
  int Q = blockIdx.x * 256 + threadIdx.x;
  int b = Q >> 12;
  float4 q = *(const float4*)&x4[(size_t)Q * 4];
  TK8_DECL
  int gbase = (b << 12) + seg * SEGLEN;
  for (int ch = 0; ch < SEGLEN / 128; ++ch) {
    __syncthreads();
    if (threadIdx.x < 128)
      sc[threadIdx.x] = *(const float4*)&x4[(size_t)(gbase + ch * 128 + threadIdx.x) * 4];
    __syncthreads();
    int m0 = seg * SEGLEN + ch * 128;
    for (int j = 0; j < 128; ++j) {
      float4 c = sc[j];
      float dot = fmaf(q.z, c.z, fmaf(q.y, c.y, q.x * c.x));
      float d = fmaxf(q.w + c.w - 2.f * dot, 0.f);
      TK8_INS(d, m0 + j)
    }
  }
  float* pdq = pd + ((size_t)Q * NSEG + seg) * 16;
  int* piq = pi + ((size_t)Q * NSEG + seg) * 16;
  TK8_STORE
}

// ------- knn over v_world [x,y,z,norm2] rows (LDS-staged), K=16, partial per segment -------
__global__ __launch_bounds__(256) void k_knnv(
    const float* __restrict__ x4, float* __restrict__ pd, int* __restrict__ pi)
{
  __shared__ __align__(16) float4 sc[128];
  int seg = blockIdx.y;
  int Q = blockIdx.x * 256 + threadIdx.x;
  int b = Q >> 12;
  float4 q = *(const float4*)&x4[(size_t)Q * 4];
  TK16_DECL
  int gbase = (b << 12) + seg * SEGLEN;
  for (int ch = 0; ch < SEGLEN / 128; ++ch) {
    __syncthreads();
    if (threadIdx.x < 128)
      sc[threadIdx.x] = *(const float4*)&x4[(size_t)(gbase + ch * 128 + threadIdx.x) * 4];
    __syncthreads();
    int m0 = seg * SEGLEN + ch * 128;
    for (int j = 0; j < 128; ++j) {
      float4 c = sc[j];
      float dot = fmaf(q.z, c.z, fmaf(q.y, c.y, q.x * c.x));
      float d = fmaxf(q.w + c.w - 2.f * dot, 0.f);
      TK16_INS(d, m0 + j)
    }
  }
  float* pdq = pd + ((size_t)Q * NSEG + seg) * 16;
  int* piq = pi + ((size_t)Q * NSEG + seg) * 16;
  TK16_STORE
}

// ---------------- merge K=8 + rigid velocity regression (+ padded v4 out) ----------------
__global__ __launch_bounds__(256) void k_rigid(
    const float* __restrict__ pd, const int* __restrict__ pi,
    const float* __restrict__ x4, const float* __restrict__ vel1,
    float* __restrict__ vout, float* __restrict__ v4out)
{
  int Q = blockIdx.x * 256 + threadIdx.x;
  int b = Q >> 12;
  TK8_DECL
  for (int s = 0; s < NSEG; ++s) {
    const float* pdq = pd + ((size_t)Q * NSEG + s) * 16;
    const int* piq = pi + ((size_t)Q * NSEG + s) * 16;
#pragma unroll
    for (int j = 0; j < KC; ++j) TK8_INS(pdq[j], piq[j])
  }
  int base = b << 12;
  double a00 = 0, a01 = 0, a02 = 0, a11 = 0, a12 = 0, a22 = 0;
  double r0 = 0, r1 = 0, r2 = 0;
#define RIG_ACC(i) { \
    float4 c = *(const float4*)&x4[(size_t)(base + tki##i) * 4]; \
    float nr = sqrtf(c.w); \
    float ux = c.x / nr, uy = c.y / nr, uz = c.z / nr; \
    float cv = vel1[base + tki##i]; \
    double dx = ux, dy = uy, dz = uz, dvv = cv; \
    a00 += dx * dx; a01 += dx * dy; a02 += dx * dz; \
    a11 += dy * dy; a12 += dy * dz; a22 += dz * dz; \
    r0 += dx * dvv; r1 += dy * dvv; r2 += dz * dvv; }
  TK8_FOREACH(RIG_ACC)
#undef RIG_ACC
  a00 += 1e-6; a11 += 1e-6; a22 += 1e-6;
  double c00 = a11 * a22 - a12 * a12;
  double c01 = a02 * a12 - a01 * a22;
  double c02 = a01 * a12 - a02 * a11;
  double c11 = a00 * a22 - a02 * a02;
  double c12 = a02 * a01 - a00 * a12;
  double c22 = a00 * a11 - a01 * a01;
  double det = a00 * c00 + a01 * c01 + a02 * c02;
  double inv = 1.0 / det;
  float vx = (float)((c00 * r0 + c01 * r1 + c02 * r2) * inv);
  float vy = (float)((c01 * r0 + c11 * r1 + c12 * r2) * inv);
  float vz = (float)((c02 * r0 + c12 * r1 + c22 * r2) * inv);
  vout[(size_t)Q * 3 + 0] = vx;
  vout[(size_t)Q * 3 + 1] = vy;
  vout[(size_t)Q * 3 + 2] = vz;
  float4 v; v.x = vx; v.y = vy; v.z = vz;
  v.w = fmaf(vz, vz, fmaf(vy, vy, vx * vx));
  *(float4*)&v4out[(size_t)Q * 4] = v;
}

// ------- knnf as register-tiled distance-GEMM + fused partial top-k -------
__global__ __launch_bounds__(256) void k_knnf(
    const float* __restrict__ f1, const float* __restrict__ f2,
    const float* __restrict__ n1,
    float* __restrict__ pd, int* __restrict__ pi)
{
  __shared__ __align__(16) float4 sf1[64 * 17];   // [q][k4], linear-staged
  __shared__ __align__(16) float4 sf2[64 * 17];   // [c][k4], linear-staged
  __shared__ __align__(16) float  sD[64][68];     // [c][q], +4 pad
  int tid = threadIdx.x;
  int tx = tid & 15, ty = tid >> 4;               // c-group, q-group
  int blockq = blockIdx.x * 64;                   // global query base (gid)
  int b = blockq >> 12;
  int seg = blockIdx.y;
  int gbase = (b << 12) + seg * 1024;             // candidate row base (gid)
  const float4* f1v = (const float4*)f1;
  const float4* f2v = (const float4*)f2;
  {
    const float4* src = f1v + (size_t)blockq * 17;
    for (int idx = tid; idx < 1088; idx += 256) sf1[idx] = src[idx];
  }
  float n1q[4];
#pragma unroll
  for (int j = 0; j < 4; ++j) n1q[j] = n1[blockq + ty + 16 * j];
  TK16_DECL
  int p = tid >> 6, qq = tid & 63;
  for (int ch = 0; ch < 16; ++ch) {
    __syncthreads();      // prev chunk's sf2/sD reads complete
    {
      const float4* src = f2v + (size_t)(gbase + ch * 64) * 17;
      for (int idx = tid; idx < 1088; idx += 256) sf2[idx] = src[idx];
    }
    __syncthreads();      // sf2 ready
    float acc[4][4];
#pragma unroll
    for (int j = 0; j < 4; ++j)
#pragma unroll
      for (int i = 0; i < 4; ++i) acc[j][i] = 0.f;
#pragma unroll 4
    for (int k4 = 0; k4 < 16; ++k4) {
      float4 fq[4], fc[4];
#pragma unroll
      for (int j = 0; j < 4; ++j) fq[j] = sf1[(ty + 16 * j) * 17 + k4];
#pragma unroll
      for (int i = 0; i < 4; ++i) fc[i] = sf2[(tx + 16 * i) * 17 + k4];
#pragma unroll
      for (int j = 0; j < 4; ++j)
#pragma unroll
        for (int i = 0; i < 4; ++i) {
          acc[j][i] = fmaf(fq[j].x, fc[i].x, acc[j][i]);
          acc[j][i] = fmaf(fq[j].y, fc[i].y, acc[j][i]);
          acc[j][i] = fmaf(fq[j].z, fc[i].z, acc[j][i]);
          acc[j][i] = fmaf(fq[j].w, fc[i].w, acc[j][i]);
        }
    }
    float cw[4];
    {   // peeled k4 = 16: {f64,f65,f66, n2}; f1 pad .w = 0 so the .w FMA adds 0
      float4 fq[4], fc[4];
#pragma unroll
      for (int j = 0; j < 4; ++j) fq[j] = sf1[(ty + 16 * j) * 17 + 16];
#pragma unroll
      for (int i = 0; i < 4; ++i) { fc[i] = sf2[(tx + 16 * i) * 17 + 16]; cw[i] = fc[i].w; }
#pragma unroll
      for (int j = 0; j < 4; ++j)
#pragma unroll
        for (int i = 0; i < 4; ++i) {
          acc[j][i] = fmaf(fq[j].x, fc[i].x, acc[j][i]);
          acc[j][i] = fmaf(fq[j].y, fc[i].y, acc[j][i]);
          acc[j][i] = fmaf(fq[j].z, fc[i].z, acc[j][i]);
          acc[j][i] = fmaf(fq[j].w, fc[i].w, acc[j][i]);
        }
    }
#pragma unroll
    for (int j = 0; j < 4; ++j)
#pragma unroll
      for (int i = 0; i < 4; ++i) {
        float d = fmaxf(n1q[j] + cw[i] - 2.f * acc[j][i], 0.f);
        sD[tx + 16 * i][ty + 16 * j] = d;
      }
    __syncthreads();      // sD ready
    int mbase = seg * 1024 + ch * 64 + p * 16;
#pragma unroll
    for (int cl = 0; cl < 16; ++cl)
      TK16_INS(sD[p * 16 + cl][qq], mbase + cl)
  }
  int pseg = seg * 4 + p;
  float* pdq = pd + ((size_t)(blockq + qq) * NSEG + pseg) * 16;
  int* piq = pi + ((size_t)(blockq + qq) * NSEG + pseg) * 16;
  TK16_STORE
}

// ---------------- merge K=16 → final indices ----------------
__global__ __launch_bounds__(256) void k_merge16(
    const float* __restrict__ pd, const int* __restrict__ pi, int* __restrict__ oidx)
{
  int Q = blockIdx.x * 256 + threadIdx.x;
  TK16_DECL
  for (int s = 0; s < NSEG; ++s) {
    const float* pdq = pd + ((size_t)Q * NSEG + s) * 16;
    const int* piq = pi + ((size_t)Q * NSEG + s) * 16;
#pragma unroll
    for (int j = 0; j < KNN; ++j) TK16_INS(pdq[j], piq[j])
  }
#define MRG_ST(i) oidx[(size_t)Q * KNN + i] = tki##i;
  TK16_FOREACH(MRG_ST)
#undef MRG_ST
}

// ---------------- fused cost-volume MLP + weightnet1 + k-sum ----------------
__global__ __launch_bounds__(256) void k_mlp(
    const float* __restrict__ p1t, const float* __restrict__ p2t,
    const float* __restrict__ x1t, const float* __restrict__ x2t,
    const int* __restrict__ kidx,
    const float* __restrict__ W1, const float* __restrict__ B1v,
    const float* __restrict__ W2, const float* __restrict__ B2v,
    const float* __restrict__ wnw1, const float* __restrict__ wnb1,
    const float* __restrict__ wnw2, const float* __restrict__ wnb2,
    const float* __restrict__ wnw3, const float* __restrict__ wnb3,
    float* __restrict__ ptp)
{
  __shared__ __align__(16) float s_p1[64];
  __shared__ __align__(16) float s_g2t[64][20];
  __shared__ __align__(16) float s_dirt[3][20];
  __shared__ __align__(16) float s_h1t[128][20];
  __shared__ __align__(16) float s_wn[16][8];
  __shared__ __align__(16) float s_red[2][128];
  int gid = blockIdx.x, b = gid >> 12, tid = threadIdx.x;
  int ch = tid & 127, kh = tid >> 7, kb = kh * 8;

  if (tid < 16) ((float4*)s_p1)[tid] = *(const float4*)&p1t[(size_t)gid * 64 + tid * 4];
  int k_ld = tid >> 4, c_ld = (tid & 15) * 4;
  int m = kidx[(size_t)gid * 16 + k_ld];
  int grow = (b << 12) + m;
  float4 gv = *(const float4*)&p2t[(size_t)grow * 64 + c_ld];
  s_g2t[c_ld + 0][k_ld] = gv.x;
  s_g2t[c_ld + 1][k_ld] = gv.y;
  s_g2t[c_ld + 2][k_ld] = gv.z;
  s_g2t[c_ld + 3][k_ld] = gv.w;
  if ((tid & 15) == 0) {
    float4 c2 = *(const float4*)&x2t[(size_t)grow * 4];
    float4 c1 = *(const float4*)&x1t[(size_t)gid * 4];
    s_dirt[0][k_ld] = c2.x - c1.x;
    s_dirt[1][k_ld] = c2.y - c1.y;
    s_dirt[2][k_ld] = c2.z - c1.z;
  }
  __syncthreads();
  if (tid < 16) {
    float dx = s_dirt[0][tid], dy = s_dirt[1][tid], dz = s_dirt[2][tid];
    float h1w[8];
#pragma unroll
    for (int j = 0; j < 8; ++j)
      h1w[j] = fmaxf(fmaf(dz, wnw1[16 + j], fmaf(dy, wnw1[8 + j], fmaf(dx, wnw1[j], wnb1[j]))), 0.f);
#pragma unroll
    for (int j = 0; j < 8; ++j) {
      float a = wnb2[j];
#pragma unroll
      for (int qq = 0; qq < 8; ++qq) a = fmaf(h1w[qq], wnw2[qq * 8 + j], a);
      s_wn[tid][j] = fmaxf(a, 0.f);
    }
  }
  // layer1 p1-center part (same for all k)
  float pre = B1v[ch];
#pragma unroll
  for (int c4 = 0; c4 < 16; ++c4) {
    float4 p = ((float4*)s_p1)[c4];
    const float* wr = &W1[(size_t)c4 * 4 * 128 + ch];
    pre = fmaf(p.x, wr[0], pre);
    pre = fmaf(p.y, wr[128], pre);
    pre = fmaf(p.z, wr[256], pre);
    pre = fmaf(p.w, wr[384], pre);
  }
  float acc[8];
#pragma unroll
  for (int j = 0; j < 8; ++j) acc[j] = pre;
  for (int c = 0; c < 64; ++c) {
    float4 g0 = *(const float4*)&s_g2t[c][kb];
    float4 g1 = *(const float4*)&s_g2t[c][kb + 4];
    float w = W1[(size_t)(64 + c) * 128 + ch];
    acc[0] = fmaf(g0.x, w, acc[0]); acc[1] = fmaf(g0.y, w, acc[1]);
    acc[2] = fmaf(g0.z, w, acc[2]); acc[3] = fmaf(g0.w, w, acc[3]);
    acc[4] = fmaf(g1.x, w, acc[4]); acc[5] = fmaf(g1.y, w, acc[5]);
    acc[6] = fmaf(g1.z, w, acc[6]); acc[7] = fmaf(g1.w, w, acc[7]);
  }
#pragma unroll
  for (int jd = 0; jd < 3; ++jd) {
    float4 d0 = *(const float4*)&s_dirt[jd][kb];
    float4 d1 = *(const float4*)&s_dirt[jd][kb + 4];
    float w = W1[(size_t)(128 + jd) * 128 + ch];
    acc[0] = fmaf(d0.x, w, acc[0]); acc[1] = fmaf(d0.y, w, acc[1]);
    acc[2] = fmaf(d0.z, w, acc[2]); acc[3] = fmaf(d0.w, w, acc[3]);
    acc[4] = fmaf(d1.x, w, acc[4]); acc[5] = fmaf(d1.y, w, acc[5]);
    acc[6] = fmaf(d1.z, w, acc[6]); acc[7] = fmaf(d1.w, w, acc[7]);
  }
#pragma unroll
  for (int j = 0; j < 8; ++j) s_h1t[ch][kb + j] = leakyf(acc[j]);
  __syncthreads();
  float acc2[8];
  float b2 = B2v[ch];
#pragma unroll
  for (int j = 0; j < 8; ++j) acc2[j] = b2;
  for (int c = 0; c < 128; ++c) {
    float4 h0 = *(const float4*)&s_h1t[c][kb];
    float4 h1 = *(const float4*)&s_h1t[c][kb + 4];
    float w = W2[(size_t)c * 128 + ch];
    acc2[0] = fmaf(h0.x, w, acc2[0]); acc2[1] = fmaf(h0.y, w, acc2[1]);
    acc2[2] = fmaf(h0.z, w, acc2[2]); acc2[3] = fmaf(h0.w, w, acc2[3]);
    acc2[4] = fmaf(h1.x, w, acc2[4]); acc2[5] = fmaf(h1.y, w, acc2[5]);
    acc2[6] = fmaf(h1.z, w, acc2[6]); acc2[7] = fmaf(h1.w, w, acc2[7]);
  }
  float r = 0.f;
#pragma unroll
  for (int j = 0; j < 8; ++j) {
    float v = leakyf(acc2[j]);
    int k = kb + j;
    float4 wa = *(const float4*)&s_wn[k][0];
    float4 wb = *(const float4*)&s_wn[k][4];
    float wv = wnb3[ch];
    wv = fmaf(wa.x, wnw3[ch], wv);
    wv = fmaf(wa.y, wnw3[128 + ch], wv);
    wv = fmaf(wa.z, wnw3[256 + ch], wv);
    wv = fmaf(wa.w, wnw3[384 + ch], wv);
    wv = fmaf(wb.x, wnw3[512 + ch], wv);
    wv = fmaf(wb.y, wnw3[640 + ch], wv);
    wv = fmaf(wb.z, wnw3[768 + ch], wv);
    wv = fmaf(wb.w, wnw3[896 + ch], wv);
    wv = fmaxf(wv, 0.f);
    r = fmaf(wv, v, r);
  }
  s_red[kh][ch] = r;
  __syncthreads();
  if (tid < 128) ptp[(size_t)gid * 128 + tid] = s_red[0][tid] + s_red[1][tid];
}

// ---------------- final: weightnet2 + gather + k-sum + transpose store ----------------
__global__ __launch_bounds__(256) void k_final(
    const float* __restrict__ x1t, const int* __restrict__ idx2,
    const float* __restrict__ ptp,
    const float* __restrict__ wnw1, const float* __restrict__ wnb1,
    const float* __restrict__ wnw2, const float* __restrict__ wnb2,
    const float* __restrict__ wnw3, const float* __restrict__ wnb3,
    float* __restrict__ out0)
{
  __shared__ __align__(16) float s_gc[16][128];
  __shared__ __align__(16) float s_wn[16][8];
  __shared__ __align__(16) float s_red[2][128];
  int gid = blockIdx.x, b = gid >> 12, n = gid & (NPTS - 1);
  int tid = threadIdx.x;
  if (tid < 16) {
    int m = idx2[(size_t)gid * 16 + tid];
    float4 c2 = *(const float4*)&x1t[(size_t)((b << 12) + m) * 4];
    float4 c1 = *(const float4*)&x1t[(size_t)gid * 4];
    float dx = c2.x - c1.x, dy = c2.y - c1.y, dz = c2.z - c1.z;
    float h1w[8];
#pragma unroll
    for (int j = 0; j < 8; ++j)
      h1w[j] = fmaxf(fmaf(dz, wnw1[16 + j], fmaf(dy, wnw1[8 + j], fmaf(dx, wnw1[j], wnb1[j]))), 0.f);
#pragma unroll
    for (int j = 0; j < 8; ++j) {
      float a = wnb2[j];
#pragma unroll
      for (int qq = 0; qq < 8; ++qq) a = fmaf(h1w[qq], wnw2[qq * 8 + j], a);
      s_wn[tid][j] = fmaxf(a, 0.f);
    }
  }
  int k2 = tid >> 4, i2 = tid & 15;
  int mg = idx2[(size_t)gid * 16 + k2];
  const float* src = &ptp[(size_t)((b << 12) + mg) * 128 + i2 * 8];
  *(float4*)&s_gc[k2][i2 * 8] = *(const float4*)&src[0];
  *(float4*)&s_gc[k2][i2 * 8 + 4] = *(const float4*)&src[4];
  __syncthreads();
  int ch = tid & 127, kg2 = tid >> 7;
  float r = 0.f;
#pragma unroll
  for (int jj = 0; jj < 8; ++jj) {
    int k = kg2 * 8 + jj;
    float4 wa = *(const float4*)&s_wn[k][0];
    float4 wb = *(const float4*)&s_wn[k][4];
    float wv = wnb3[ch];
    wv = fmaf(wa.x, wnw3[ch], wv);
    wv = fmaf(wa.y, wnw3[128 + ch], wv);
    wv = fmaf(wa.z, wnw3[256 + ch], wv);
    wv = fmaf(wa.w, wnw3[384 + ch], wv);
    wv = fmaf(wb.x, wnw3[512 + ch], wv);
    wv = fmaf(wb.y, wnw3[640 + ch], wv);
    wv = fmaf(wb.z, wnw3[768 + ch], wv);
    wv = fmaf(wb.w, wnw3[896 + ch], wv);
    wv = fmaxf(wv, 0.f);
    r = fmaf(wv, s_gc[k][ch], r);
  }
  s_red[kg2][ch] = r;
  __syncthreads();
  if (tid < 128)
    out0[(size_t)(b * 128 + tid) * NPTS + n] = s_red[0][tid] + s_red[1][tid];
}

extern "C" void kernel_launch(void* const* d_in, const int* in_sizes, int n_in,
                              void* d_out, int out_size, void* d_ws, size_t ws_size,
                              hipStream_t stream) {
  (void)in_sizes; (void)n_in; (void)out_size; (void)ws_size;
  const float* xyz1   = (const float*)d_in[0];
  const float* xyz2   = (const float*)d_in[1];
  const float* pts1   = (const float*)d_in[2];
  const float* pts2   = (const float*)d_in[3];
  const float* vel1   = (const float*)d_in[4];
  const float* w_xyz  = (const float*)d_in[8];
  const float* w_pts  = (const float*)d_in[10];
  const float* mlp_w1 = (const float*)d_in[11];
  const float* mlp_b1 = (const float*)d_in[12];
  const float* mlp_w2 = (const float*)d_in[13];
  const float* mlp_b2 = (const float*)d_in[14];
  const float* wn1_w1 = (const float*)d_in[15];
  const float* wn1_b1 = (const float*)d_in[16];
  const float* wn1_w2 = (const float*)d_in[17];
  const float* wn1_b2 = (const float*)d_in[18];
  const float* wn1_w3 = (const float*)d_in[19];
  const float* wn1_b3 = (const float*)d_in[20];
  const float* wn2_w1 = (const float*)d_in[21];
  const float* wn2_b1 = (const float*)d_in[22];
  const float* wn2_w2 = (const float*)d_in[23];
  const float* wn2_b2 = (const float*)d_in[24];
  const float* wn2_w3 = (const float*)d_in[25];
  const float* wn2_b3 = (const float*)d_in[26];

  char* ws = (char*)d_ws;
  size_t off = 0;
  float* pd   = (float*)(ws + off); off += (size_t)NQ * NSEG * 16 * 4;   // 8 MB
  int*   pi   = (int*)(ws + off);   off += (size_t)NQ * NSEG * 16 * 4;   // 8 MB
  float* f1   = (float*)(ws + off); off += (size_t)NQ * FPAD * 4;
  float* f2   = (float*)(ws + off); off += (size_t)NQ * FPAD * 4;
  float* n1   = (float*)(ws + off); off += (size_t)NQ * 4;
  float* p1t  = (float*)(ws + off); off += (size_t)NQ * DD * 4;
  float* p2t  = (float*)(ws + off); off += (size_t)NQ * DD * 4;
  float* x1t  = (float*)(ws + off); off += (size_t)NQ * 4 * 4;
  float* x2t  = (float*)(ws + off); off += (size_t)NQ * 4 * 4;
  int*   kidx = (int*)(ws + off);   off += (size_t)NQ * KNN * 4;
  float* ptp  = (float*)(ws + off); off += (size_t)NQ * 128 * 4;
  int*   idx2 = (int*)(ws + off);   off += (size_t)NQ * KNN * 4;
  float* v4   = (float*)(ws + off); off += (size_t)NQ * 4 * 4;

  float* out0 = (float*)d_out;
  float* outv = (float*)d_out + VOFF;

  k_prep<<<32, 256, 0, stream>>>(xyz1, xyz2, pts1, pts2, w_xyz, w_pts,
                                 f1, f2, n1, p1t, p2t, x1t, x2t);
  k_knn3<<<dim3(32, NSEG), 256, 0, stream>>>(x1t, pd, pi);
  k_rigid<<<32, 256, 0, stream>>>(pd, pi, x1t, vel1, outv, v4);
  k_knnf<<<dim3(128, 4), 256, 0, stream>>>(f1, f2, n1, pd, pi);
  k_merge16<<<32, 256, 0, stream>>>(pd, pi, kidx);
  k_mlp<<<NQ, 256, 0, stream>>>(p1t, p2t, x1t, x2t, kidx,
                                mlp_w1, mlp_b1, mlp_w2, mlp_b2,
                                wn1_w1, wn1_b1, wn1_w2, wn1_b2, wn1_w3, wn1_b3, ptp);
  k_knnv<<<dim3(32, NSEG), 256, 0, stream>>>(v4, pd, pi);
  k_merge16<<<32, 256, 0, stream>>>(pd, pi, idx2);
  k_final<<<NQ, 256, 0, stream>>>(x1t, idx2, ptp,
                                  wn2_w1, wn2_b1, wn2_w2, wn2_b2, wn2_w3, wn2_b3, out0);
}

// Round 6
// 493.608 us; speedup vs baseline: 3.6036x; 1.5625x over previous
//
#include <hip/hip_runtime.h>

#define NPTS 4096
#define NQ   8192      // B*N
#define DD   64
#define KNN  16
#define KC   8
#define NSEG 16
#define SEGLEN 256     // NPTS/NSEG (staged knn kernels)
#define FPAD 68        // 67 features + 1 pad (f2 pad slot holds n2; f1 pad = 0)
#define VOFF 1048576   // B*128*N, float offset of v_world in d_out

#define ALWAYS_INLINE __attribute__((always_inline)) inline

__device__ ALWAYS_INLINE float leakyf(float x) { return x > 0.f ? x : 0.1f * x; }

// Pack distance + 12-bit tag into one f32 sort key. d >= 0 always, so float
// compare == uint compare. Truncates mantissa to 11 bits (rel. quantum ~5e-4);
// ties broken by tag (stream-local idx, then pseg) — near-exact lax.top_k.
__device__ ALWAYS_INLINE float packdt(float d, unsigned tag12) {
  return __uint_as_float((__float_as_uint(d) & 0xFFFFF000u) | tag12);
}

// ---- top-k state as NAMED SCALARS (never arrays — hipcc scratch-allocates
// per-thread arrays: rounds 1-4 measured 5-10x slowdown from this) ----
#define TK8_FOREACH(M)  M(0) M(1) M(2) M(3) M(4) M(5) M(6) M(7)
#define TK16_FOREACH(M) M(0) M(1) M(2) M(3) M(4) M(5) M(6) M(7) \
                        M(8) M(9) M(10) M(11) M(12) M(13) M(14) M(15)

// exact (d,i) chain, K=8 — used only on the rigid-regression path
#define TK_DECL1(i) float tkd##i = 3.4e38f; int tki##i = 0;
#define TK_STEP1(i) { bool c = vd < tkd##i; float t_ = tkd##i; int u_ = tki##i; \
                      tkd##i = c ? vd : tkd##i; tki##i = c ? vi : tki##i; \
                      vd = c ? t_ : vd; vi = c ? u_ : vi; }
#define TK8_DECL  TK8_FOREACH(TK_DECL1)
#define TK8_INS(dexp, mexp)  { float vd = (dexp); int vi = (mexp); \
                               if (vd < tkd7)  { TK8_FOREACH(TK_STEP1) } }

// packed min/max chain, K=16: 2 VALU per slot, branchless, no index regs
#define PK_DECL1(i) float pk##i = __uint_as_float(0x7F7FFFFFu);
#define PK_STEP1(i) { float lo_ = fminf(pk##i, pv); pv = fmaxf(pk##i, pv); pk##i = lo_; }
#define PK16_DECL    TK16_FOREACH(PK_DECL1)
#define PK16_INS(ve) { float pv = (ve); TK16_FOREACH(PK_STEP1) }
#define PK_STORE1(i) pdq[i] = pk##i;
#define PK16_STORE   TK16_FOREACH(PK_STORE1)

// ---------------- prep: transposes + weighted features + norms ----------------
__global__ __launch_bounds__(256) void k_prep(
    const float* __restrict__ xyz1, const float* __restrict__ xyz2,
    const float* __restrict__ pts1, const float* __restrict__ pts2,
    const float* __restrict__ w_xyz_p, const float* __restrict__ w_points_p,
    float* __restrict__ f1, float* __restrict__ f2,
    float* __restrict__ n1,
    float* __restrict__ p1t, float* __restrict__ p2t,
    float* __restrict__ x1t, float* __restrict__ x2t)
{
  int gid = blockIdx.x * 256 + threadIdx.x;   // 0..8191
  int b = gid >> 12, n = gid & (NPTS - 1);
  float wx = w_xyz_p[0], wp = w_points_p[0];
  {
    const float* xb = xyz1 + (size_t)b * 3 * NPTS;
    float x = xb[n], y = xb[NPTS + n], z = xb[2 * NPTS + n];
    float nrm2 = fmaf(z, z, fmaf(y, y, x * x));
    float4 xv; xv.x = x; xv.y = y; xv.z = z; xv.w = nrm2;
    *(float4*)&x1t[(size_t)gid * 4] = xv;
    float fx = wx * x, fy = wx * y, fz = wx * z;
    float acc = fmaf(fz, fz, fmaf(fy, fy, fx * fx));
    float* fr = f1 + (size_t)gid * FPAD;
    fr[0] = fx; fr[1] = fy; fr[2] = fz;
    const float* pb = pts1 + (size_t)b * DD * NPTS;
    float* pr = p1t + (size_t)gid * DD;
    for (int c = 0; c < DD; ++c) {
      float v = pb[(size_t)c * NPTS + n];
      pr[c] = v;
      float fv = wp * v;
      fr[3 + c] = fv;
      acc = fmaf(fv, fv, acc);
    }
    fr[67] = 0.f;           // query pad must stay 0 (so pad term adds 0 to dot)
    n1[gid] = acc;
  }
  {
    const float* xb = xyz2 + (size_t)b * 3 * NPTS;
    float x = xb[n], y = xb[NPTS + n], z = xb[2 * NPTS + n];
    float nrm2 = fmaf(z, z, fmaf(y, y, x * x));
    float4 xv; xv.x = x; xv.y = y; xv.z = z; xv.w = nrm2;
    *(float4*)&x2t[(size_t)gid * 4] = xv;
    float fx = wx * x, fy = wx * y, fz = wx * z;
    float acc = fmaf(fz, fz, fmaf(fy, fy, fx * fx));
    float* fr = f2 + (size_t)gid * FPAD;
    fr[0] = fx; fr[1] = fy; fr[2] = fz;
    const float* pb = pts2 + (size_t)b * DD * NPTS;
    float* pr = p2t + (size_t)gid * DD;
    for (int c = 0; c < DD; ++c) {
      float v = pb[(size_t)c * NPTS + n];
      pr[c] = v;
      float fv = wp * v;
      fr[3 + c] = fv;
      acc = fmaf(fv, fv, acc);
    }
    fr[67] = acc;           // candidate pad carries n2
  }
}

// ------- knn over xyz1 (LDS-staged), K=8, EXACT (feeds rigid regression) -------
__global__ __launch_bounds__(256) void k_knn3(
    const float* __restrict__ x4, float* __restrict__ pd, int* __restrict__ pi)
{
  __shared__ __align__(16) float4 sc[128];
  int seg = blockIdx.y;
  int Q = blockIdx.x * 256 + threadIdx.x;
  int b = Q >> 12;
  float4 q = *(const float4*)&x4[(size_t)Q * 4];
  TK8_DECL
  int gbase = (b << 12) + seg * SEGLEN;
  for (int ch = 0; ch < SEGLEN / 128; ++ch) {
    __syncthreads();
    if (threadIdx.x < 128)
      sc[threadIdx.x] = *(const float4*)&x4[(size_t)(gbase + ch * 128 + threadIdx.x) * 4];
    __syncthreads();
    int m0 = seg * SEGLEN + ch * 128;
    for (int j = 0; j < 128; ++j) {
      float4 c = sc[j];
      float dot = fmaf(q.z, c.z, fmaf(q.y, c.y, q.x * c.x));
      float d = fmaxf(q.w + c.w - 2.f * dot, 0.f);
      TK8_INS(d, m0 + j)
    }
  }
  float* pdq = pd + ((size_t)Q * NSEG + seg) * 16;
  int* piq = pi + ((size_t)Q * NSEG + seg) * 16;
#define ST8(i) pdq[i] = tkd##i; piq[i] = tki##i;
  TK8_FOREACH(ST8)
#undef ST8
}

// ------- knn over v_world (LDS-staged), K=16, packed keys -------
__global__ __launch_bounds__(256) void k_knnv(
    const float* __restrict__ x4, float* __restrict__ pd)
{
  __shared__ __align__(16) float4 sc[128];
  int seg = blockIdx.y;
  int Q = blockIdx.x * 256 + threadIdx.x;
  int b = Q >> 12;
  float4 q = *(const float4*)&x4[(size_t)Q * 4];
  PK16_DECL
  int gbase = (b << 12) + seg * SEGLEN;
  for (int ch = 0; ch < SEGLEN / 128; ++ch) {
    __syncthreads();
    if (threadIdx.x < 128)
      sc[threadIdx.x] = *(const float4*)&x4[(size_t)(gbase + ch * 128 + threadIdx.x) * 4];
    __syncthreads();
    unsigned base_tag = ((unsigned)ch << 11) | (unsigned)seg;  // (local<<4)|seg, local=ch*128+j
#pragma unroll
    for (int j = 0; j < 128; ++j) {
      float4 c = sc[j];
      float dot = fmaf(q.z, c.z, fmaf(q.y, c.y, q.x * c.x));
      float d = fmaxf(q.w + c.w - 2.f * dot, 0.f);
      PK16_INS(packdt(d, base_tag | ((unsigned)j << 4)))
    }
  }
  float* pdq = pd + ((size_t)Q * NSEG + seg) * 16;
  PK16_STORE
}

// ---------------- merge K=8 + rigid velocity regression (+ padded v4 out) ----------------
__global__ __launch_bounds__(256) void k_rigid(
    const float* __restrict__ pd, const int* __restrict__ pi,
    const float* __restrict__ x4, const float* __restrict__ vel1,
    float* __restrict__ vout, float* __restrict__ v4out)
{
  int Q = blockIdx.x * 256 + threadIdx.x;
  int b = Q >> 12;
  TK8_DECL
  for (int s = 0; s < NSEG; ++s) {
    const float* pdq = pd + ((size_t)Q * NSEG + s) * 16;
    const int* piq = pi + ((size_t)Q * NSEG + s) * 16;
#pragma unroll
    for (int j = 0; j < KC; ++j) TK8_INS(pdq[j], piq[j])
  }
  int base = b << 12;
  double a00 = 0, a01 = 0, a02 = 0, a11 = 0, a12 = 0, a22 = 0;
  double r0 = 0, r1 = 0, r2 = 0;
#define RIG_ACC(i) { \
    float4 c = *(const float4*)&x4[(size_t)(base + tki##i) * 4]; \
    float nr = sqrtf(c.w); \
    float ux = c.x / nr, uy = c.y / nr, uz = c.z / nr; \
    float cv = vel1[base + tki##i]; \
    double dx = ux, dy = uy, dz = uz, dvv = cv; \
    a00 += dx * dx; a01 += dx * dy; a02 += dx * dz; \
    a11 += dy * dy; a12 += dy * dz; a22 += dz * dz; \
    r0 += dx * dvv; r1 += dy * dvv; r2 += dz * dvv; }
  TK8_FOREACH(RIG_ACC)
#undef RIG_ACC
  a00 += 1e-6; a11 += 1e-6; a22 += 1e-6;
  double c00 = a11 * a22 - a12 * a12;
  double c01 = a02 * a12 - a01 * a22;
  double c02 = a01 * a12 - a02 * a11;
  double c11 = a00 * a22 - a02 * a02;
  double c12 = a02 * a01 - a00 * a12;
  double c22 = a00 * a11 - a01 * a01;
  double det = a00 * c00 + a01 * c01 + a02 * c02;
  double inv = 1.0 / det;
  float vx = (float)((c00 * r0 + c01 * r1 + c02 * r2) * inv);
  float vy = (float)((c01 * r0 + c11 * r1 + c12 * r2) * inv);
  float vz = (float)((c02 * r0 + c12 * r1 + c22 * r2) * inv);
  vout[(size_t)Q * 3 + 0] = vx;
  vout[(size_t)Q * 3 + 1] = vy;
  vout[(size_t)Q * 3 + 2] = vz;
  float4 v; v.x = vx; v.y = vy; v.z = vz;
  v.w = fmaf(vz, vz, fmaf(vy, vy, vx * vx));
  *(float4*)&v4out[(size_t)Q * 4] = v;
}

// ------- knnf: register-tiled distance-GEMM + packed partial top-k -------
// grid (128 q-tiles, 4 segs). sD holds PACKED keys (tag folded in at write).
__global__ __launch_bounds__(256) void k_knnf(
    const float* __restrict__ f1, const float* __restrict__ f2,
    const float* __restrict__ n1,
    float* __restrict__ pd)
{
  __shared__ __align__(16) float4 sf1[64 * 17];   // [q][k4], linear-staged
  __shared__ __align__(16) float4 sf2[64 * 17];   // [c][k4], linear-staged
  __shared__ __align__(16) float  sD[64][68];     // [c][q] packed keys, +4 pad
  int tid = threadIdx.x;
  int tx = tid & 15, ty = tid >> 4;               // c-group, q-group
  int blockq = blockIdx.x * 64;                   // global query base (gid)
  int b = blockq >> 12;
  int seg = blockIdx.y;
  int gbase = (b << 12) + seg * 1024;             // candidate row base (gid)
  const float4* f1v = (const float4*)f1;
  const float4* f2v = (const float4*)f2;
  {
    const float4* src = f1v + (size_t)blockq * 17;
    for (int idx = tid; idx < 1088; idx += 256) sf1[idx] = src[idx];
  }
  float n1q[4];
#pragma unroll
  for (int j = 0; j < 4; ++j) n1q[j] = n1[blockq + ty + 16 * j];
  PK16_DECL
  int p = tid >> 6, qq = tid & 63;
  for (int ch = 0; ch < 16; ++ch) {
    __syncthreads();      // prev chunk's sf2/sD reads complete
    {
      const float4* src = f2v + (size_t)(gbase + ch * 64) * 17;
      for (int idx = tid; idx < 1088; idx += 256) sf2[idx] = src[idx];
    }
    __syncthreads();      // sf2 ready
    float acc[4][4];
#pragma unroll
    for (int j = 0; j < 4; ++j)
#pragma unroll
      for (int i = 0; i < 4; ++i) acc[j][i] = 0.f;
#pragma unroll 4
    for (int k4 = 0; k4 < 16; ++k4) {
      float4 fq[4], fc[4];
#pragma unroll
      for (int j = 0; j < 4; ++j) fq[j] = sf1[(ty + 16 * j) * 17 + k4];
#pragma unroll
      for (int i = 0; i < 4; ++i) fc[i] = sf2[(tx + 16 * i) * 17 + k4];
#pragma unroll
      for (int j = 0; j < 4; ++j)
#pragma unroll
        for (int i = 0; i < 4; ++i) {
          acc[j][i] = fmaf(fq[j].x, fc[i].x, acc[j][i]);
          acc[j][i] = fmaf(fq[j].y, fc[i].y, acc[j][i]);
          acc[j][i] = fmaf(fq[j].z, fc[i].z, acc[j][i]);
          acc[j][i] = fmaf(fq[j].w, fc[i].w, acc[j][i]);
        }
    }
    float cw[4];
    {   // peeled k4 = 16: {f64,f65,f66, n2}; f1 pad .w = 0 so the .w FMA adds 0
      float4 fq[4], fc[4];
#pragma unroll
      for (int j = 0; j < 4; ++j) fq[j] = sf1[(ty + 16 * j) * 17 + 16];
#pragma unroll
      for (int i = 0; i < 4; ++i) { fc[i] = sf2[(tx + 16 * i) * 17 + 16]; cw[i] = fc[i].w; }
#pragma unroll
      for (int j = 0; j < 4; ++j)
#pragma unroll
        for (int i = 0; i < 4; ++i) {
          acc[j][i] = fmaf(fq[j].x, fc[i].x, acc[j][i]);
          acc[j][i] = fmaf(fq[j].y, fc[i].y, acc[j][i]);
          acc[j][i] = fmaf(fq[j].z, fc[i].z, acc[j][i]);
          acc[j][i] = fmaf(fq[j].w, fc[i].w, acc[j][i]);
        }
    }
    // write PACKED keys: candidate c = tx+16i -> local = ch*16+tx (8b), psub = i
    // tag12 = (local<<4) | (seg*4 + i)
#pragma unroll
    for (int i = 0; i < 4; ++i) {
      unsigned tag = (((unsigned)(ch * 16 + tx)) << 4) | (unsigned)(seg * 4 + i);
#pragma unroll
      for (int j = 0; j < 4; ++j) {
        float d = fmaxf(n1q[j] + cw[i] - 2.f * acc[j][i], 0.f);
        sD[tx + 16 * i][ty + 16 * j] = packdt(d, tag);
      }
    }
    __syncthreads();      // sD ready
#pragma unroll
    for (int cl = 0; cl < 16; ++cl)
      PK16_INS(sD[p * 16 + cl][qq])
  }
  int pseg = seg * 4 + p;
  float* pdq = pd + ((size_t)(blockq + qq) * NSEG + pseg) * 16;
  PK16_STORE
}

// ---------------- packed merges: 16 sorted psegs -> top-16, decode global idx ----------------
// MODE 0 (knnf): tag = (local8<<4)|pseg4, local=ch*16+cl, pseg=seg*4+p
//                m = seg*1024 + ch*64 + p*16 + cl
// MODE 1 (knnv): tag = (local8<<4)|seg4, m = seg*256 + local
template<int MODE>
__global__ __launch_bounds__(256) void k_mergepk(
    const float* __restrict__ pd, int* __restrict__ oidx)
{
  int Q = blockIdx.x * 256 + threadIdx.x;
  PK16_DECL
  for (int s = 0; s < NSEG; ++s) {
    const float* pdq = pd + ((size_t)Q * NSEG + s) * 16;
    for (int j = 0; j < 16; ++j) {          // sorted ascending -> early break
      float v = pdq[j];
      if (__all(!(v < pk15))) break;
      PK16_INS(v)
    }
  }
#define DEC(i) { unsigned u = __float_as_uint(pk##i); int m_; \
    if (MODE == 0) { unsigned ps = u & 15u, lo = (u >> 4) & 255u; \
      m_ = (int)(((ps >> 2) << 10) + ((lo >> 4) << 6) + ((ps & 3u) << 4) + (lo & 15u)); } \
    else { m_ = (int)(((u & 15u) << 8) + ((u >> 4) & 255u)); } \
    oidx[(size_t)Q * KNN + i] = m_; }
  TK16_FOREACH(DEC)
#undef DEC
}

// ---------------- fused cost-volume MLP + weightnet1 + k-sum ----------------
__global__ __launch_bounds__(256) void k_mlp(
    const float* __restrict__ p1t, const float* __restrict__ p2t,
    const float* __restrict__ x1t, const float* __restrict__ x2t,
    const int* __restrict__ kidx,
    const float* __restrict__ W1, const float* __restrict__ B1v,
    const float* __restrict__ W2, const float* __restrict__ B2v,
    const float* __restrict__ wnw1, const float* __restrict__ wnb1,
    const float* __restrict__ wnw2, const float* __restrict__ wnb2,
    const float* __restrict__ wnw3, const float* __restrict__ wnb3,
    float* __restrict__ ptp)
{
  __shared__ __align__(16) float s_p1[64];
  __shared__ __align__(16) float s_g2t[64][20];
  __shared__ __align__(16) float s_dirt[3][20];
  __shared__ __align__(16) float s_h1t[128][20];
  __shared__ __align__(16) float s_wn[16][8];
  __shared__ __align__(16) float s_red[2][128];
  int gid = blockIdx.x, b = gid >> 12, tid = threadIdx.x;
  int ch = tid & 127, kh = tid >> 7, kb = kh * 8;

  if (tid < 16) ((float4*)s_p1)[tid] = *(const float4*)&p1t[(size_t)gid * 64 + tid * 4];
  int k_ld = tid >> 4, c_ld = (tid & 15) * 4;
  int m = kidx[(size_t)gid * 16 + k_ld];
  int grow = (b << 12) + m;
  float4 gv = *(const float4*)&p2t[(size_t)grow * 64 + c_ld];
  s_g2t[c_ld + 0][k_ld] = gv.x;
  s_g2t[c_ld + 1][k_ld] = gv.y;
  s_g2t[c_ld + 2][k_ld] = gv.z;
  s_g2t[c_ld + 3][k_ld] = gv.w;
  if ((tid & 15) == 0) {
    float4 c2 = *(const float4*)&x2t[(size_t)grow * 4];
    float4 c1 = *(const float4*)&x1t[(size_t)gid * 4];
    s_dirt[0][k_ld] = c2.x - c1.x;
    s_dirt[1][k_ld] = c2.y - c1.y;
    s_dirt[2][k_ld] = c2.z - c1.z;
  }
  __syncthreads();
  if (tid < 16) {
    float dx = s_dirt[0][tid], dy = s_dirt[1][tid], dz = s_dirt[2][tid];
    float h1w[8];
#pragma unroll
    for (int j = 0; j < 8; ++j)
      h1w[j] = fmaxf(fmaf(dz, wnw1[16 + j], fmaf(dy, wnw1[8 + j], fmaf(dx, wnw1[j], wnb1[j]))), 0.f);
#pragma unroll
    for (int j = 0; j < 8; ++j) {
      float a = wnb2[j];
#pragma unroll
      for (int qq = 0; qq < 8; ++qq) a = fmaf(h1w[qq], wnw2[qq * 8 + j], a);
      s_wn[tid][j] = fmaxf(a, 0.f);
    }
  }
  // layer1 p1-center part (same for all k)
  float pre = B1v[ch];
#pragma unroll
  for (int c4 = 0; c4 < 16; ++c4) {
    float4 p = ((float4*)s_p1)[c4];
    const float* wr = &W1[(size_t)c4 * 4 * 128 + ch];
    pre = fmaf(p.x, wr[0], pre);
    pre = fmaf(p.y, wr[128], pre);
    pre = fmaf(p.z, wr[256], pre);
    pre = fmaf(p.w, wr[384], pre);
  }
  float acc[8];
#pragma unroll
  for (int j = 0; j < 8; ++j) acc[j] = pre;
  for (int c = 0; c < 64; ++c) {
    float4 g0 = *(const float4*)&s_g2t[c][kb];
    float4 g1 = *(const float4*)&s_g2t[c][kb + 4];
    float w = W1[(size_t)(64 + c) * 128 + ch];
    acc[0] = fmaf(g0.x, w, acc[0]); acc[1] = fmaf(g0.y, w, acc[1]);
    acc[2] = fmaf(g0.z, w, acc[2]); acc[3] = fmaf(g0.w, w, acc[3]);
    acc[4] = fmaf(g1.x, w, acc[4]); acc[5] = fmaf(g1.y, w, acc[5]);
    acc[6] = fmaf(g1.z, w, acc[6]); acc[7] = fmaf(g1.w, w, acc[7]);
  }
#pragma unroll
  for (int jd = 0; jd < 3; ++jd) {
    float4 d0 = *(const float4*)&s_dirt[jd][kb];
    float4 d1 = *(const float4*)&s_dirt[jd][kb + 4];
    float w = W1[(size_t)(128 + jd) * 128 + ch];
    acc[0] = fmaf(d0.x, w, acc[0]); acc[1] = fmaf(d0.y, w, acc[1]);
    acc[2] = fmaf(d0.z, w, acc[2]); acc[3] = fmaf(d0.w, w, acc[3]);
    acc[4] = fmaf(d1.x, w, acc[4]); acc[5] = fmaf(d1.y, w, acc[5]);
    acc[6] = fmaf(d1.z, w, acc[6]); acc[7] = fmaf(d1.w, w, acc[7]);
  }
#pragma unroll
  for (int j = 0; j < 8; ++j) s_h1t[ch][kb + j] = leakyf(acc[j]);
  __syncthreads();
  float acc2[8];
  float b2 = B2v[ch];
#pragma unroll
  for (int j = 0; j < 8; ++j) acc2[j] = b2;
  for (int c = 0; c < 128; ++c) {
    float4 h0 = *(const float4*)&s_h1t[c][kb];
    float4 h1 = *(const float4*)&s_h1t[c][kb + 4];
    float w = W2[(size_t)c * 128 + ch];
    acc2[0] = fmaf(h0.x, w, acc2[0]); acc2[1] = fmaf(h0.y, w, acc2[1]);
    acc2[2] = fmaf(h0.z, w, acc2[2]); acc2[3] = fmaf(h0.w, w, acc2[3]);
    acc2[4] = fmaf(h1.x, w, acc2[4]); acc2[5] = fmaf(h1.y, w, acc2[5]);
    acc2[6] = fmaf(h1.z, w, acc2[6]); acc2[7] = fmaf(h1.w, w, acc2[7]);
  }
  float r = 0.f;
#pragma unroll
  for (int j = 0; j < 8; ++j) {
    float v = leakyf(acc2[j]);
    int k = kb + j;
    float4 wa = *(const float4*)&s_wn[k][0];
    float4 wb = *(const float4*)&s_wn[k][4];
    float wv = wnb3[ch];
    wv = fmaf(wa.x, wnw3[ch], wv);
    wv = fmaf(wa.y, wnw3[128 + ch], wv);
    wv = fmaf(wa.z, wnw3[256 + ch], wv);
    wv = fmaf(wa.w, wnw3[384 + ch], wv);
    wv = fmaf(wb.x, wnw3[512 + ch], wv);
    wv = fmaf(wb.y, wnw3[640 + ch], wv);
    wv = fmaf(wb.z, wnw3[768 + ch], wv);
    wv = fmaf(wb.w, wnw3[896 + ch], wv);
    wv = fmaxf(wv, 0.f);
    r = fmaf(wv, v, r);
  }
  s_red[kh][ch] = r;
  __syncthreads();
  if (tid < 128) ptp[(size_t)gid * 128 + tid] = s_red[0][tid] + s_red[1][tid];
}

// ---------------- final: weightnet2 + gather + k-sum + transpose store ----------------
__global__ __launch_bounds__(256) void k_final(
    const float* __restrict__ x1t, const int* __restrict__ idx2,
    const float* __restrict__ ptp,
    const float* __restrict__ wnw1, const float* __restrict__ wnb1,
    const float* __restrict__ wnw2, const float* __restrict__ wnb2,
    const float* __restrict__ wnw3, const float* __restrict__ wnb3,
    float* __restrict__ out0)
{
  __shared__ __align__(16) float s_gc[16][128];
  __shared__ __align__(16) float s_wn[16][8];
  __shared__ __align__(16) float s_red[2][128];
  int gid = blockIdx.x, b = gid >> 12, n = gid & (NPTS - 1);
  int tid = threadIdx.x;
  if (tid < 16) {
    int m = idx2[(size_t)gid * 16 + tid];
    float4 c2 = *(const float4*)&x1t[(size_t)((b << 12) + m) * 4];
    float4 c1 = *(const float4*)&x1t[(size_t)gid * 4];
    float dx = c2.x - c1.x, dy = c2.y - c1.y, dz = c2.z - c1.z;
    float h1w[8];
#pragma unroll
    for (int j = 0; j < 8; ++j)
      h1w[j] = fmaxf(fmaf(dz, wnw1[16 + j], fmaf(dy, wnw1[8 + j], fmaf(dx, wnw1[j], wnb1[j]))), 0.f);
#pragma unroll
    for (int j = 0; j < 8; ++j) {
      float a = wnb2[j];
#pragma unroll
      for (int qq = 0; qq < 8; ++qq) a = fmaf(h1w[qq], wnw2[qq * 8 + j], a);
      s_wn[tid][j] = fmaxf(a, 0.f);
    }
  }
  int k2 = tid >> 4, i2 = tid & 15;
  int mg = idx2[(size_t)gid * 16 + k2];
  const float* src = &ptp[(size_t)((b << 12) + mg) * 128 + i2 * 8];
  *(float4*)&s_gc[k2][i2 * 8] = *(const float4*)&src[0];
  *(float4*)&s_gc[k2][i2 * 8 + 4] = *(const float4*)&src[4];
  __syncthreads();
  int ch = tid & 127, kg2 = tid >> 7;
  float r = 0.f;
#pragma unroll
  for (int jj = 0; jj < 8; ++jj) {
    int k = kg2 * 8 + jj;
    float4 wa = *(const float4*)&s_wn[k][0];
    float4 wb = *(const float4*)&s_wn[k][4];
    float wv = wnb3[ch];
    wv = fmaf(wa.x, wnw3[ch], wv);
    wv = fmaf(wa.y, wnw3[128 + ch], wv);
    wv = fmaf(wa.z, wnw3[256 + ch], wv);
    wv = fmaf(wa.w, wnw3[384 + ch], wv);
    wv = fmaf(wb.x, wnw3[512 + ch], wv);
    wv = fmaf(wb.y, wnw3[640 + ch], wv);
    wv = fmaf(wb.z, wnw3[768 + ch], wv);
    wv = fmaf(wb.w, wnw3[896 + ch], wv);
    wv = fmaxf(wv, 0.f);
    r = fmaf(wv, s_gc[k][ch], r);
  }
  s_red[kg2][ch] = r;
  __syncthreads();
  if (tid < 128)
    out0[(size_t)(b * 128 + tid) * NPTS + n] = s_red[0][tid] + s_red[1][tid];
}

extern "C" void kernel_launch(void* const* d_in, const int* in_sizes, int n_in,
                              void* d_out, int out_size, void* d_ws, size_t ws_size,
                              hipStream_t stream) {
  (void)in_sizes; (void)n_in; (void)out_size; (void)ws_size;
  const float* xyz1   = (const float*)d_in[0];
  const float* xyz2   = (const float*)d_in[1];
  const float* pts1   = (const float*)d_in[2];
  const float* pts2   = (const float*)d_in[3];
  const float* vel1   = (const float*)d_in[4];
  const float* w_xyz  = (const float*)d_in[8];
  const float* w_pts  = (const float*)d_in[10];
  const float* mlp_w1 = (const float*)d_in[11];
  const float* mlp_b1 = (const float*)d_in[12];
  const float* mlp_w2 = (const float*)d_in[13];
  const float* mlp_b2 = (const float*)d_in[14];
  const float* wn1_w1 = (const float*)d_in[15];
  const float* wn1_b1 = (const float*)d_in[16];
  const float* wn1_w2 = (const float*)d_in[17];
  const float* wn1_b2 = (const float*)d_in[18];
  const float* wn1_w3 = (const float*)d_in[19];
  const float* wn1_b3 = (const float*)d_in[20];
  const float* wn2_w1 = (const float*)d_in[21];
  const float* wn2_b1 = (const float*)d_in[22];
  const float* wn2_w2 = (const float*)d_in[23];
  const float* wn2_b2 = (const float*)d_in[24];
  const float* wn2_w3 = (const float*)d_in[25];
  const float* wn2_b3 = (const float*)d_in[26];

  char* ws = (char*)d_ws;
  size_t off = 0;
  float* pd   = (float*)(ws + off); off += (size_t)NQ * NSEG * 16 * 4;   // 8 MB
  int*   pi   = (int*)(ws + off);   off += (size_t)NQ * NSEG * 16 * 4;   // 8 MB
  float* f1   = (float*)(ws + off); off += (size_t)NQ * FPAD * 4;
  float* f2   = (float*)(ws + off); off += (size_t)NQ * FPAD * 4;
  float* n1   = (float*)(ws + off); off += (size_t)NQ * 4;
  float* p1t  = (float*)(ws + off); off += (size_t)NQ * DD * 4;
  float* p2t  = (float*)(ws + off); off += (size_t)NQ * DD * 4;
  float* x1t  = (float*)(ws + off); off += (size_t)NQ * 4 * 4;
  float* x2t  = (float*)(ws + off); off += (size_t)NQ * 4 * 4;
  int*   kidx = (int*)(ws + off);   off += (size_t)NQ * KNN * 4;
  float* ptp  = (float*)(ws + off); off += (size_t)NQ * 128 * 4;
  int*   idx2 = (int*)(ws + off);   off += (size_t)NQ * KNN * 4;
  float* v4   = (float*)(ws + off); off += (size_t)NQ * 4 * 4;

  float* out0 = (float*)d_out;
  float* outv = (float*)d_out + VOFF;

  k_prep<<<32, 256, 0, stream>>>(xyz1, xyz2, pts1, pts2, w_xyz, w_pts,
                                 f1, f2, n1, p1t, p2t, x1t, x2t);
  k_knn3<<<dim3(32, NSEG), 256, 0, stream>>>(x1t, pd, pi);
  k_rigid<<<32, 256, 0, stream>>>(pd, pi, x1t, vel1, outv, v4);
  k_knnf<<<dim3(128, 4), 256, 0, stream>>>(f1, f2, n1, pd);
  k_mergepk<0><<<32, 256, 0, stream>>>(pd, kidx);
  k_mlp<<<NQ, 256, 0, stream>>>(p1t, p2t, x1t, x2t, kidx,
                                mlp_w1, mlp_b1, mlp_w2, mlp_b2,
                                wn1_w1, wn1_b1, wn1_w2, wn1_b2, wn1_w3, wn1_b3, ptp);
  k_knnv<<<dim3(32, NSEG), 256, 0, stream>>>(v4, pd);
  k_mergepk<1><<<32, 256, 0, stream>>>(pd, idx2);
  k_final<<<NQ, 256, 0, stream>>>(x1t, idx2, ptp,
                                  wn2_w1, wn2_b1, wn2_w2, wn2_b2, wn2_w3, wn2_b3, out0);
}